// Round 4
// baseline (2560.260 us; speedup 1.0000x reference)
//
#include <hip/hip_runtime.h>
#include <math.h>

// B=64 graphs, A=32 atoms, N=2048 nodes, E=65536 edges, H=512, LAT=256, L=4, DIS=60, EIN=1093

typedef short bf16x8 __attribute__((ext_vector_type(8)));
typedef float f32x4 __attribute__((ext_vector_type(4)));

__device__ __forceinline__ float silu_f(float x) {
    float e = __builtin_amdgcn_exp2f(x * -1.44269504088896f);
    return x * __builtin_amdgcn_rcpf(1.0f + e);
}
__device__ __forceinline__ unsigned short f2bf(float x) {
    unsigned int u = __float_as_uint(x);
    u += 0x7fffu + ((u >> 16) & 1u);
    return (unsigned short)(u >> 16);
}
__device__ __forceinline__ unsigned int cvt_pk_bf16(float lo, float hi) {
    unsigned int r;
    asm("v_cvt_pk_bf16_f32 %0, %1, %2" : "=v"(r) : "v"(lo), "v"(hi));
    return r;
}

// ---- workspace layout (float offsets) ----
#define NF_OFF    0
#define UAGG_OFF  (2048*512)
#define VT_OFF    (2*2048*512)                 // ushort region 64*512*32 = 524288 floats
#define H1_OFF    (VT_OFF + 524288)            // ushort region 2048*512  = 524288 floats
#define WBF_OFF   (H1_OFF + 524288)
// bf16 weight region sizes (ushort elements)
#define SZ_INITT (512*768)
#define SZ_UVT   (1024*512)
#define SZ_W1DT  (512*64)
#define SZ_W2T   (512*512)
#define SZ_NW1T  (512*1024)
#define SZ_NW2T  (512*512)
#define SZ_LAYER (SZ_UVT+SZ_W1DT+SZ_W2T+SZ_NW1T+SZ_NW2T)

// ---- weight transpose+convert: f32 [K][512] -> bf16 [512 n][Kd k] ----
__global__ __launch_bounds__(256) void k_prep(
    const float* __restrict__ Wl, const float* __restrict__ eW1,
    const float* __restrict__ eW2, const float* __restrict__ nW1,
    const float* __restrict__ nW2, unsigned short* __restrict__ wbf)
{
    __shared__ float tile[32][33];
    int bid = blockIdx.x;
    const float* src; int K; unsigned short* dst; int Kd; int t;
    if (bid < 384) { src = Wl; K = 768; dst = wbf; Kd = 768; t = bid; }
    else {
        int b = bid - 384; int l = b / 1568; int j = b - l * 1568;
        const float* e1 = eW1 + (size_t)l * 1093 * 512;
        unsigned short* base = wbf + SZ_INITT + (size_t)l * SZ_LAYER;
        if (j < 256)      { src = e1;                       K = 512;  dst = base;                                   Kd = 512;  t = j; }
        else if (j < 512) { src = e1 + 512*512;             K = 512;  dst = base + 512*512;                         Kd = 512;  t = j-256; }
        else if (j < 544) { src = e1 + 1033*512;            K = 60;   dst = base + SZ_UVT;                          Kd = 64;   t = j-512; }
        else if (j < 800) { src = eW2 + (size_t)l*512*512;  K = 512;  dst = base + SZ_UVT+SZ_W1DT;                  Kd = 512;  t = j-544; }
        else if (j <1312) { src = nW1 + (size_t)l*1024*512; K = 1024; dst = base + SZ_UVT+SZ_W1DT+SZ_W2T;           Kd = 1024; t = j-800; }
        else              { src = nW2 + (size_t)l*512*512;  K = 512;  dst = base + SZ_UVT+SZ_W1DT+SZ_W2T+SZ_NW1T;   Kd = 512;  t = j-1312; }
    }
    int tr = t >> 4, tc = t & 15;
    int k0 = tr * 32, nn0 = tc * 32;
    int r8 = threadIdx.x >> 5, cc = threadIdx.x & 31;
    #pragma unroll
    for (int rr = 0; rr < 4; ++rr) {
        int row = rr*8 + r8;
        int k = k0 + row;
        tile[row][cc] = (k < K) ? src[(size_t)k*512 + nn0 + cc] : 0.f;
    }
    __syncthreads();
    #pragma unroll
    for (int rr = 0; rr < 4; ++rr) {
        int row = rr*8 + r8;
        dst[(size_t)(nn0+row)*Kd + k0 + cc] = f2bf(tile[cc][row]);
    }
}

// nf0 = concat(emb,t)@Wl + bl : 16 rows x 256 cols per block, 256 blocks
__global__ __launch_bounds__(256) void k_init(
    const float* __restrict__ tvec, const float* __restrict__ emb,
    const unsigned short* __restrict__ WT, const float* __restrict__ bl,
    const int* __restrict__ atom_types, float* __restrict__ nf)
{
    __shared__ __align__(16) unsigned short cat_s[16*768];
    int n0 = (blockIdx.x >> 1) * 16, half = blockIdx.x & 1, tid = threadIdx.x;
    for (int idx = tid; idx < 16*192; idx += 256) {
        int m = idx / 192, q = idx - m * 192;
        int k4 = q * 4, n = n0 + m;
        float4 v;
        if (k4 < 512) v = *(const float4*)&emb[(size_t)(atom_types[n]-1)*512 + k4];
        else          v = *(const float4*)&tvec[(size_t)(n>>5)*256 + (k4-512)];
        uint2 pk = { cvt_pk_bf16(v.x, v.y), cvt_pk_bf16(v.z, v.w) };
        *(uint2*)&cat_s[m*768 + (k4 ^ ((m&7)<<3))] = pk;
    }
    __syncthreads();
    int w = tid >> 6, l = tid & 63, lj = l & 15, lh = l >> 4;
    f32x4 acc[4];
    #pragma unroll
    for (int nt = 0; nt < 4; ++nt) acc[nt] = (f32x4){0.f,0.f,0.f,0.f};
    for (int kt = 0; kt < 24; ++kt) {
        int k = kt*32 + lh*8;
        bf16x8 a = *(const bf16x8*)&cat_s[lj*768 + (k ^ ((lj&7)<<3))];
        #pragma unroll
        for (int nt = 0; nt < 4; ++nt) {
            int c = half*256 + w*64 + nt*16 + lj;
            bf16x8 b = *(const bf16x8*)&WT[(size_t)c*768 + k];
            acc[nt] = __builtin_amdgcn_mfma_f32_16x16x32_bf16(a, b, acc[nt], 0, 0, 0);
        }
    }
    #pragma unroll
    for (int nt = 0; nt < 4; ++nt) {
        int c = half*256 + w*64 + nt*16 + lj;
        float bv = bl[c];
        #pragma unroll
        for (int r = 0; r < 4; ++r)
            nf[(size_t)(n0 + lh*4 + r)*512 + c] = acc[nt][r] + bv;
    }
}

// half0: U' = nf@W1a + latip@W1c + b1 (f32); half1: VT[g][c][j] = bf16(nf@W1b)
__global__ __launch_bounds__(256) void k_uv(
    const float* __restrict__ nf, const unsigned short* __restrict__ WT,
    const float* __restrict__ lat, const float* __restrict__ W1c,
    const float* __restrict__ b1, float* __restrict__ Up,
    unsigned short* __restrict__ VT)
{
    __shared__ __align__(16) unsigned short a_s[16*512];
    int n0 = (blockIdx.x >> 1) * 16, half = blockIdx.x & 1;
    int g = n0 >> 5, j0 = n0 & 31, tid = threadIdx.x;
    for (int idx = tid; idx < 16*128; idx += 256) {
        int m = idx >> 7, q = idx & 127;
        int k4 = q * 4;
        float4 v = *(const float4*)&nf[(size_t)(n0+m)*512 + k4];
        uint2 pk = { cvt_pk_bf16(v.x, v.y), cvt_pk_bf16(v.z, v.w) };
        *(uint2*)&a_s[m*512 + (k4 ^ ((m&7)<<3))] = pk;
    }
    __syncthreads();
    int w = tid >> 6, l = tid & 63, lj = l & 15, lh = l >> 4;
    const unsigned short* Wh = WT + (size_t)half*512*512;
    f32x4 acc[8];
    #pragma unroll
    for (int nt = 0; nt < 8; ++nt) acc[nt] = (f32x4){0.f,0.f,0.f,0.f};
    for (int kt = 0; kt < 16; ++kt) {
        int k = kt*32 + lh*8;
        bf16x8 a = *(const bf16x8*)&a_s[lj*512 + (k ^ ((lj&7)<<3))];
        #pragma unroll
        for (int nt = 0; nt < 8; ++nt) {
            int c = w*128 + nt*16 + lj;
            bf16x8 b = *(const bf16x8*)&Wh[(size_t)c*512 + k];
            acc[nt] = __builtin_amdgcn_mfma_f32_16x16x32_bf16(a, b, acc[nt], 0, 0, 0);
        }
    }
    if (half == 0) {
        float L[9], lip[9];
        #pragma unroll
        for (int i = 0; i < 9; ++i) L[i] = lat[g*9 + i];
        #pragma unroll
        for (int i = 0; i < 3; ++i)
            #pragma unroll
            for (int kk = 0; kk < 3; ++kk)
                lip[i*3+kk] = L[i*3]*L[kk*3] + L[i*3+1]*L[kk*3+1] + L[i*3+2]*L[kk*3+2];
        #pragma unroll
        for (int nt = 0; nt < 8; ++nt) {
            int c = w*128 + nt*16 + lj;
            float p3 = b1[c];
            #pragma unroll
            for (int t9 = 0; t9 < 9; ++t9) p3 += lip[t9] * W1c[t9*512 + c];
            #pragma unroll
            for (int r = 0; r < 4; ++r)
                Up[(size_t)(n0 + lh*4 + r)*512 + c] = acc[nt][r] + p3;
        }
    } else {
        #pragma unroll
        for (int nt = 0; nt < 8; ++nt) {
            int c = w*128 + nt*16 + lj;
            uint2 pk = { cvt_pk_bf16(acc[nt][0], acc[nt][1]),
                         cvt_pk_bf16(acc[nt][2], acc[nt][3]) };
            *(uint2*)&VT[((size_t)g*512 + c)*32 + j0 + lh*4] = pk;
        }
    }
}

// fused edge pipeline: 2 src nodes per block, 5-phase double-buffered (c-blocks of 128)
// stage1 (swapped): ef1^T[c][m] = W1dT(A) x fd(B) + VT(A) x ind(B); +base, silu -> buf
// stage2: acc2[m][c2] += ef1(A from buf) x W2T(B)
__global__ __launch_bounds__(256, 4) void k_edge(
    const float* __restrict__ Up, const unsigned short* __restrict__ VT,
    const float* __restrict__ frac,
    const unsigned short* __restrict__ W1dT,
    const unsigned short* __restrict__ W2T, const float* __restrict__ b2,
    float* __restrict__ agg)
{
    __shared__ __align__(16) unsigned short buf[2][64*128];
    int n0 = blockIdx.x * 2, g = n0 >> 5, tid = threadIdx.x;
    int w = tid >> 6, l = tid & 63, lj = l & 15, lh = l >> 4;
    const unsigned short* VTg = VT + (size_t)g*512*32;

    // per-lane frac diffs: h = src offset (0/1), dd = dst half (m&16)
    float di[2][2][3];
    #pragma unroll
    for (int h = 0; h < 2; ++h)
        #pragma unroll
        for (int dd = 0; dd < 2; ++dd) {
            int dstn = g*32 + dd*16 + lj, srcn = n0 + h;
            #pragma unroll
            for (int comp = 0; comp < 3; ++comp) {
                float d = frac[dstn*3 + comp] - frac[srcn*3 + comp];
                d -= floorf(d);
                di[h][dd][comp] = d;
            }
        }
    // fd B-fragments in registers: fdf[kt][mt][kk] = fd[mt*16+lj][kt*32+lh*8+kk]
    bf16x8 fdf[2][4];
    #pragma unroll
    for (int kt = 0; kt < 2; ++kt)
        #pragma unroll
        for (int mt = 0; mt < 4; ++mt) {
            int h = mt >> 1, dd = mt & 1;
            #pragma unroll
            for (int kk = 0; kk < 8; ++kk) {
                int k = kt*32 + lh*8 + kk;
                float val = 0.f;
                if (k < 60) {
                    int isCos = k >= 30;
                    int dq = k - (isCos ? 30 : 0);
                    int comp = dq >= 20 ? 2 : (dq >= 10 ? 1 : 0);
                    int f = dq - comp*10;
                    float u = di[h][dd][comp] * (float)f;
                    u -= floorf(u);
                    val = isCos ? __builtin_amdgcn_cosf(u) : __builtin_amdgcn_sinf(u);
                }
                fdf[kt][mt][kk] = (short)f2bf(val);
            }
        }
    // indicator B-frags for V-gather: ind[dd][kk] = (lh*8+kk == dd*16+lj)
    bf16x8 ind[2];
    #pragma unroll
    for (int dd = 0; dd < 2; ++dd)
        #pragma unroll
        for (int kk = 0; kk < 8; ++kk)
            ind[dd][kk] = (short)((lh*8 + kk == dd*16 + lj) ? 0x3F80 : 0);

    f32x4 acc2[4][8];
    #pragma unroll
    for (int mt = 0; mt < 4; ++mt)
        #pragma unroll
        for (int nt = 0; nt < 8; ++nt) acc2[mt][nt] = (f32x4){0.f,0.f,0.f,0.f};

    for (int p = 0; p < 5; ++p) {
        if (p < 4) {
            f32x4 a1[2][4];
            #pragma unroll
            for (int q = 0; q < 2; ++q)
                #pragma unroll
                for (int mt = 0; mt < 4; ++mt) a1[q][mt] = (f32x4){0.f,0.f,0.f,0.f};
            #pragma unroll
            for (int q = 0; q < 2; ++q) {
                int crow = p*128 + (w*2+q)*16 + lj;
                bf16x8 vf = *(const bf16x8*)&VTg[(size_t)crow*32 + lh*8];
                #pragma unroll
                for (int mt = 0; mt < 4; ++mt)
                    a1[q][mt] = __builtin_amdgcn_mfma_f32_16x16x32_bf16(vf, ind[mt&1], a1[q][mt], 0, 0, 0);
                #pragma unroll
                for (int kt = 0; kt < 2; ++kt) {
                    bf16x8 wf = *(const bf16x8*)&W1dT[(size_t)crow*64 + kt*32 + lh*8];
                    #pragma unroll
                    for (int mt = 0; mt < 4; ++mt)
                        a1[q][mt] = __builtin_amdgcn_mfma_f32_16x16x32_bf16(wf, fdf[kt][mt], a1[q][mt], 0, 0, 0);
                }
            }
            unsigned short* bdst = &buf[p&1][0];
            #pragma unroll
            for (int q = 0; q < 2; ++q) {
                int c0l = (w*2+q)*16 + lh*4;
                float4 bs0 = *(const float4*)&Up[(size_t)n0*512 + p*128 + c0l];
                float4 bs1 = *(const float4*)&Up[(size_t)(n0+1)*512 + p*128 + c0l];
                #pragma unroll
                for (int mt = 0; mt < 4; ++mt) {
                    float4 bb = (mt >> 1) ? bs1 : bs0;
                    float x0 = silu_f(a1[q][mt][0] + bb.x);
                    float x1 = silu_f(a1[q][mt][1] + bb.y);
                    float x2 = silu_f(a1[q][mt][2] + bb.z);
                    float x3 = silu_f(a1[q][mt][3] + bb.w);
                    uint2 pk = { cvt_pk_bf16(x0, x1), cvt_pk_bf16(x2, x3) };
                    int m = mt*16 + lj;
                    *(uint2*)&bdst[m*128 + (c0l ^ ((lj&7)<<3))] = pk;
                }
            }
        }
        if (p > 0) {
            int pp = p - 1;
            const unsigned short* bsrc = &buf[pp&1][0];
            #pragma unroll
            for (int kt = 0; kt < 4; ++kt) {
                bf16x8 af[4];
                #pragma unroll
                for (int mt = 0; mt < 4; ++mt)
                    af[mt] = *(const bf16x8*)&bsrc[(mt*16+lj)*128 + ((kt*32+lh*8) ^ ((lj&7)<<3))];
                #pragma unroll
                for (int nt = 0; nt < 8; ++nt) {
                    int c2 = w*128 + nt*16 + lj;
                    bf16x8 bfr = *(const bf16x8*)&W2T[(size_t)c2*512 + pp*128 + kt*32 + lh*8];
                    #pragma unroll
                    for (int mt = 0; mt < 4; ++mt)
                        acc2[mt][nt] = __builtin_amdgcn_mfma_f32_16x16x32_bf16(af[mt], bfr, acc2[mt][nt], 0, 0, 0);
                }
            }
        }
        if (p < 4) __syncthreads();
    }

    // epilogue: silu + per-node column mean
    #pragma unroll
    for (int nt = 0; nt < 8; ++nt) {
        int c = w*128 + nt*16 + lj;
        float bv = b2[c];
        float s0 = 0.f, s1 = 0.f;
        #pragma unroll
        for (int mt = 0; mt < 4; ++mt)
            #pragma unroll
            for (int r = 0; r < 4; ++r) {
                float x = silu_f(acc2[mt][nt][r] + bv);
                if (mt < 2) s0 += x; else s1 += x;
            }
        s0 += __shfl_xor(s0, 16); s0 += __shfl_xor(s0, 32);
        s1 += __shfl_xor(s1, 16); s1 += __shfl_xor(s1, 32);
        if (lh == 0) {
            agg[(size_t)n0*512 + c]     = s0 * (1.0f/32.0f);
            agg[(size_t)(n0+1)*512 + c] = s1 * (1.0f/32.0f);
        }
    }
}

// h1 = silu([nf,agg]@nW1 + b1) -> bf16 global ; 16 rows x 256 cols, 256 blocks
__global__ __launch_bounds__(256) void k_node1(
    const float* __restrict__ nf, const float* __restrict__ agg,
    const unsigned short* __restrict__ W1T, const float* __restrict__ b1,
    unsigned short* __restrict__ h1g)
{
    __shared__ __align__(16) unsigned short nin_s[16*1024];
    int n0 = (blockIdx.x >> 1) * 16, half = blockIdx.x & 1, tid = threadIdx.x;
    for (int idx = tid; idx < 16*256; idx += 256) {
        int m = idx >> 8, q = idx & 255;
        int k4 = q * 4;
        float4 v = (k4 < 512) ? *(const float4*)&nf[(size_t)(n0+m)*512 + k4]
                              : *(const float4*)&agg[(size_t)(n0+m)*512 + (k4-512)];
        uint2 pk = { cvt_pk_bf16(v.x, v.y), cvt_pk_bf16(v.z, v.w) };
        *(uint2*)&nin_s[m*1024 + (k4 ^ ((m&7)<<3))] = pk;
    }
    __syncthreads();
    int w = tid >> 6, l = tid & 63, lj = l & 15, lh = l >> 4;
    f32x4 acc[4];
    #pragma unroll
    for (int nt = 0; nt < 4; ++nt) acc[nt] = (f32x4){0.f,0.f,0.f,0.f};
    for (int kt = 0; kt < 32; ++kt) {
        int k = kt*32 + lh*8;
        bf16x8 a = *(const bf16x8*)&nin_s[lj*1024 + (k ^ ((lj&7)<<3))];
        #pragma unroll
        for (int nt = 0; nt < 4; ++nt) {
            int c = half*256 + w*64 + nt*16 + lj;
            bf16x8 b = *(const bf16x8*)&W1T[(size_t)c*1024 + k];
            acc[nt] = __builtin_amdgcn_mfma_f32_16x16x32_bf16(a, b, acc[nt], 0, 0, 0);
        }
    }
    #pragma unroll
    for (int nt = 0; nt < 4; ++nt) {
        int c = half*256 + w*64 + nt*16 + lj;
        float bv = b1[c];
        #pragma unroll
        for (int r = 0; r < 4; ++r)
            h1g[(size_t)(n0 + lh*4 + r)*512 + c] = f2bf(silu_f(acc[nt][r] + bv));
    }
}

// nf += silu(h1@nW2 + b2) ; 16 rows x 256 cols, 256 blocks
__global__ __launch_bounds__(256) void k_node2(
    float* __restrict__ nf, const unsigned short* __restrict__ h1g,
    const unsigned short* __restrict__ W2T, const float* __restrict__ b2)
{
    __shared__ __align__(16) unsigned short h1_s[16*512];
    int n0 = (blockIdx.x >> 1) * 16, half = blockIdx.x & 1, tid = threadIdx.x;
    for (int idx = tid; idx < 16*64; idx += 256) {
        int m = idx >> 6, k8 = (idx & 63) * 8;
        bf16x8 v = *(const bf16x8*)&h1g[(size_t)(n0+m)*512 + k8];
        *(bf16x8*)&h1_s[m*512 + (k8 ^ ((m&7)<<3))] = v;
    }
    __syncthreads();
    int w = tid >> 6, l = tid & 63, lj = l & 15, lh = l >> 4;
    f32x4 acc[4];
    #pragma unroll
    for (int nt = 0; nt < 4; ++nt) acc[nt] = (f32x4){0.f,0.f,0.f,0.f};
    for (int kt = 0; kt < 16; ++kt) {
        int k = kt*32 + lh*8;
        bf16x8 a = *(const bf16x8*)&h1_s[lj*512 + (k ^ ((lj&7)<<3))];
        #pragma unroll
        for (int nt = 0; nt < 4; ++nt) {
            int c = half*256 + w*64 + nt*16 + lj;
            bf16x8 b = *(const bf16x8*)&W2T[(size_t)c*512 + k];
            acc[nt] = __builtin_amdgcn_mfma_f32_16x16x32_bf16(a, b, acc[nt], 0, 0, 0);
        }
    }
    #pragma unroll
    for (int nt = 0; nt < 4; ++nt) {
        int c = half*256 + w*64 + nt*16 + lj;
        float bv = b2[c];
        #pragma unroll
        for (int r = 0; r < 4; ++r) {
            size_t o = (size_t)(n0 + lh*4 + r)*512 + c;
            nf[o] = nf[o] + silu_f(acc[nt][r] + bv);
        }
    }
}

__global__ __launch_bounds__(256) void k_coord(const float* __restrict__ nf,
                                               const float* __restrict__ cW,
                                               float* __restrict__ out) {
    int gid = blockIdx.x * 256 + threadIdx.x;
    if (gid >= 2048 * 3) return;
    int n = gid / 3, c = gid - n * 3;
    float s = 0.f;
    for (int k = 0; k < 512; ++k) s += nf[n * 512 + k] * cW[k * 3 + c];
    out[576 + gid] = s;
}

__global__ __launch_bounds__(256) void k_graph(const float* __restrict__ nf,
                                               const float* __restrict__ lW,
                                               const float* __restrict__ lat,
                                               float* __restrict__ out) {
    __shared__ float gf[512];
    __shared__ float lo9[9];
    int b = blockIdx.x, tid = threadIdx.x;
    float s0 = 0.f, s1 = 0.f;
    for (int r = 0; r < 32; ++r) {
        s0 += nf[(b * 32 + r) * 512 + tid];
        s1 += nf[(b * 32 + r) * 512 + tid + 256];
    }
    gf[tid]       = s0 * (1.f / 32.f);
    gf[tid + 256] = s1 * (1.f / 32.f);
    __syncthreads();
    if (tid < 9) {
        float s = 0.f;
        for (int k = 0; k < 512; ++k) s += gf[k] * lW[k * 9 + tid];
        lo9[tid] = s;
    }
    __syncthreads();
    if (tid < 9) {
        int i = tid / 3, kk = tid - (tid / 3) * 3;
        float s = lo9[i*3+0] * lat[b*9 + 0*3 + kk]
                + lo9[i*3+1] * lat[b*9 + 1*3 + kk]
                + lo9[i*3+2] * lat[b*9 + 2*3 + kk];
        out[b * 9 + tid] = s;
    }
}

extern "C" void kernel_launch(void* const* d_in, const int* in_sizes, int n_in,
                              void* d_out, int out_size, void* d_ws, size_t ws_size,
                              hipStream_t stream)
{
    const float* t    = (const float*)d_in[0];
    const float* frac = (const float*)d_in[1];
    const float* lat  = (const float*)d_in[2];
    const float* emb  = (const float*)d_in[3];
    const float* Wl   = (const float*)d_in[4];
    const float* bl   = (const float*)d_in[5];
    const float* eW1  = (const float*)d_in[6];
    const float* eb1  = (const float*)d_in[7];
    const float* eW2  = (const float*)d_in[8];
    const float* eb2  = (const float*)d_in[9];
    const float* nW1  = (const float*)d_in[10];
    const float* nb1  = (const float*)d_in[11];
    const float* nW2  = (const float*)d_in[12];
    const float* nb2  = (const float*)d_in[13];
    const float* cW   = (const float*)d_in[14];
    const float* lW   = (const float*)d_in[15];
    const int* atom_types = (const int*)d_in[16];

    float* out  = (float*)d_out;
    float* wsf  = (float*)d_ws;
    float* nf   = wsf + NF_OFF;
    float* Uagg = wsf + UAGG_OFF;   // U' during k_uv/k_edge, then agg (row-exclusive)
    unsigned short* VT  = (unsigned short*)(wsf + VT_OFF);
    unsigned short* h1g = (unsigned short*)(wsf + H1_OFF);
    unsigned short* wbf = (unsigned short*)(wsf + WBF_OFF);

    k_prep<<<384 + 4*1568, 256, 0, stream>>>(Wl, eW1, eW2, nW1, nW2, wbf);
    k_init<<<256, 256, 0, stream>>>(t, emb, wbf, bl, atom_types, nf);
    for (int l = 0; l < 4; ++l) {
        const unsigned short* uvT  = wbf + SZ_INITT + (size_t)l * SZ_LAYER;
        const unsigned short* w1dT = uvT + SZ_UVT;
        const unsigned short* w2T  = w1dT + SZ_W1DT;
        const unsigned short* nw1T = w2T + SZ_W2T;
        const unsigned short* nw2T = nw1T + SZ_NW1T;
        k_uv<<<256, 256, 0, stream>>>(nf, uvT, lat,
                                      eW1 + (size_t)l*1093*512 + 1024*512,
                                      eb1 + l*512, Uagg, VT);
        k_edge<<<1024, 256, 0, stream>>>(Uagg, VT, frac, w1dT, w2T, eb2 + l*512, Uagg);
        k_node1<<<256, 256, 0, stream>>>(nf, Uagg, nw1T, nb1 + l*512, h1g);
        k_node2<<<256, 256, 0, stream>>>(nf, h1g, nw2T, nb2 + l*512);
    }
    k_coord<<<24, 256, 0, stream>>>(nf, cW, out);
    k_graph<<<64, 256, 0, stream>>>(nf, lW, lat, out);
}

// Round 5
// 952.830 us; speedup vs baseline: 2.6870x; 2.6870x over previous
//
#include <hip/hip_runtime.h>
#include <math.h>

// B=64 graphs, A=32 atoms, N=2048 nodes, E=65536 edges, H=512, LAT=256, L=4, DIS=60, EIN=1093

typedef short bf16x8 __attribute__((ext_vector_type(8)));
typedef float f32x4 __attribute__((ext_vector_type(4)));

__device__ __forceinline__ float silu_f(float x) {
    float e = __builtin_amdgcn_exp2f(x * -1.44269504088896f);
    return x * __builtin_amdgcn_rcpf(1.0f + e);
}
__device__ __forceinline__ unsigned short f2bf(float x) {
    unsigned int u = __float_as_uint(x);
    u += 0x7fffu + ((u >> 16) & 1u);
    return (unsigned short)(u >> 16);
}
__device__ __forceinline__ unsigned int cvt_pk_bf16(float lo, float hi) {
    unsigned int r;
    asm("v_cvt_pk_bf16_f32 %0, %1, %2" : "=v"(r) : "v"(lo), "v"(hi));
    return r;
}

// ---- workspace layout (float offsets) ----
#define NF_OFF    0
#define UAGG_OFF  (2048*512)
#define VT_OFF    (2*2048*512)                 // ushort region 64*512*32 = 524288 floats
#define H1_OFF    (VT_OFF + 524288)            // ushort region 2048*512  = 524288 floats
#define WBF_OFF   (H1_OFF + 524288)
// bf16 weight region sizes (ushort elements)
#define SZ_INITT (512*768)
#define SZ_UVT   (1024*512)
#define SZ_W1DT  (512*64)
#define SZ_W2T   (512*512)
#define SZ_NW1T  (512*1024)
#define SZ_NW2T  (512*512)
#define SZ_LAYER (SZ_UVT+SZ_W1DT+SZ_W2T+SZ_NW1T+SZ_NW2T)

// ---- weight transpose+convert: f32 [K][512] -> bf16 [512 n][Kd k] ----
__global__ __launch_bounds__(256) void k_prep(
    const float* __restrict__ Wl, const float* __restrict__ eW1,
    const float* __restrict__ eW2, const float* __restrict__ nW1,
    const float* __restrict__ nW2, unsigned short* __restrict__ wbf)
{
    __shared__ float tile[32][33];
    int bid = blockIdx.x;
    const float* src; int K; unsigned short* dst; int Kd; int t;
    if (bid < 384) { src = Wl; K = 768; dst = wbf; Kd = 768; t = bid; }
    else {
        int b = bid - 384; int l = b / 1568; int j = b - l * 1568;
        const float* e1 = eW1 + (size_t)l * 1093 * 512;
        unsigned short* base = wbf + SZ_INITT + (size_t)l * SZ_LAYER;
        if (j < 256)      { src = e1;                       K = 512;  dst = base;                                   Kd = 512;  t = j; }
        else if (j < 512) { src = e1 + 512*512;             K = 512;  dst = base + 512*512;                         Kd = 512;  t = j-256; }
        else if (j < 544) { src = e1 + 1033*512;            K = 60;   dst = base + SZ_UVT;                          Kd = 64;   t = j-512; }
        else if (j < 800) { src = eW2 + (size_t)l*512*512;  K = 512;  dst = base + SZ_UVT+SZ_W1DT;                  Kd = 512;  t = j-544; }
        else if (j <1312) { src = nW1 + (size_t)l*1024*512; K = 1024; dst = base + SZ_UVT+SZ_W1DT+SZ_W2T;           Kd = 1024; t = j-800; }
        else              { src = nW2 + (size_t)l*512*512;  K = 512;  dst = base + SZ_UVT+SZ_W1DT+SZ_W2T+SZ_NW1T;   Kd = 512;  t = j-1312; }
    }
    int tr = t >> 4, tc = t & 15;
    int k0 = tr * 32, nn0 = tc * 32;
    int r8 = threadIdx.x >> 5, cc = threadIdx.x & 31;
    #pragma unroll
    for (int rr = 0; rr < 4; ++rr) {
        int row = rr*8 + r8;
        int k = k0 + row;
        tile[row][cc] = (k < K) ? src[(size_t)k*512 + nn0 + cc] : 0.f;
    }
    __syncthreads();
    #pragma unroll
    for (int rr = 0; rr < 4; ++rr) {
        int row = rr*8 + r8;
        dst[(size_t)(nn0+row)*Kd + k0 + cc] = f2bf(tile[cc][row]);
    }
}

// nf0 = concat(emb,t)@Wl + bl : 16 rows x 256 cols per block, 256 blocks
__global__ __launch_bounds__(256) void k_init(
    const float* __restrict__ tvec, const float* __restrict__ emb,
    const unsigned short* __restrict__ WT, const float* __restrict__ bl,
    const int* __restrict__ atom_types, float* __restrict__ nf)
{
    __shared__ __align__(16) unsigned short cat_s[16*768];
    int n0 = (blockIdx.x >> 1) * 16, half = blockIdx.x & 1, tid = threadIdx.x;
    for (int idx = tid; idx < 16*192; idx += 256) {
        int m = idx / 192, q = idx - m * 192;
        int k4 = q * 4, n = n0 + m;
        float4 v;
        if (k4 < 512) v = *(const float4*)&emb[(size_t)(atom_types[n]-1)*512 + k4];
        else          v = *(const float4*)&tvec[(size_t)(n>>5)*256 + (k4-512)];
        uint2 pk = { cvt_pk_bf16(v.x, v.y), cvt_pk_bf16(v.z, v.w) };
        *(uint2*)&cat_s[m*768 + (k4 ^ ((m&7)<<3))] = pk;
    }
    __syncthreads();
    int w = tid >> 6, l = tid & 63, lj = l & 15, lh = l >> 4;
    f32x4 acc[4];
    #pragma unroll
    for (int nt = 0; nt < 4; ++nt) acc[nt] = (f32x4){0.f,0.f,0.f,0.f};
    for (int kt = 0; kt < 24; ++kt) {
        int k = kt*32 + lh*8;
        bf16x8 a = *(const bf16x8*)&cat_s[lj*768 + (k ^ ((lj&7)<<3))];
        #pragma unroll
        for (int nt = 0; nt < 4; ++nt) {
            int c = half*256 + w*64 + nt*16 + lj;
            bf16x8 b = *(const bf16x8*)&WT[(size_t)c*768 + k];
            acc[nt] = __builtin_amdgcn_mfma_f32_16x16x32_bf16(a, b, acc[nt], 0, 0, 0);
        }
    }
    #pragma unroll
    for (int nt = 0; nt < 4; ++nt) {
        int c = half*256 + w*64 + nt*16 + lj;
        float bv = bl[c];
        #pragma unroll
        for (int r = 0; r < 4; ++r)
            nf[(size_t)(n0 + lh*4 + r)*512 + c] = acc[nt][r] + bv;
    }
}

// half0: U' = nf@W1a + latip@W1c + b1 (f32); half1: VT[g][c][j] = bf16(nf@W1b)
__global__ __launch_bounds__(256) void k_uv(
    const float* __restrict__ nf, const unsigned short* __restrict__ WT,
    const float* __restrict__ lat, const float* __restrict__ W1c,
    const float* __restrict__ b1, float* __restrict__ Up,
    unsigned short* __restrict__ VT)
{
    __shared__ __align__(16) unsigned short a_s[16*512];
    int n0 = (blockIdx.x >> 1) * 16, half = blockIdx.x & 1;
    int g = n0 >> 5, j0 = n0 & 31, tid = threadIdx.x;
    for (int idx = tid; idx < 16*128; idx += 256) {
        int m = idx >> 7, q = idx & 127;
        int k4 = q * 4;
        float4 v = *(const float4*)&nf[(size_t)(n0+m)*512 + k4];
        uint2 pk = { cvt_pk_bf16(v.x, v.y), cvt_pk_bf16(v.z, v.w) };
        *(uint2*)&a_s[m*512 + (k4 ^ ((m&7)<<3))] = pk;
    }
    __syncthreads();
    int w = tid >> 6, l = tid & 63, lj = l & 15, lh = l >> 4;
    const unsigned short* Wh = WT + (size_t)half*512*512;
    f32x4 acc[8];
    #pragma unroll
    for (int nt = 0; nt < 8; ++nt) acc[nt] = (f32x4){0.f,0.f,0.f,0.f};
    for (int kt = 0; kt < 16; ++kt) {
        int k = kt*32 + lh*8;
        bf16x8 a = *(const bf16x8*)&a_s[lj*512 + (k ^ ((lj&7)<<3))];
        #pragma unroll
        for (int nt = 0; nt < 8; ++nt) {
            int c = w*128 + nt*16 + lj;
            bf16x8 b = *(const bf16x8*)&Wh[(size_t)c*512 + k];
            acc[nt] = __builtin_amdgcn_mfma_f32_16x16x32_bf16(a, b, acc[nt], 0, 0, 0);
        }
    }
    if (half == 0) {
        float L[9], lip[9];
        #pragma unroll
        for (int i = 0; i < 9; ++i) L[i] = lat[g*9 + i];
        #pragma unroll
        for (int i = 0; i < 3; ++i)
            #pragma unroll
            for (int kk = 0; kk < 3; ++kk)
                lip[i*3+kk] = L[i*3]*L[kk*3] + L[i*3+1]*L[kk*3+1] + L[i*3+2]*L[kk*3+2];
        #pragma unroll
        for (int nt = 0; nt < 8; ++nt) {
            int c = w*128 + nt*16 + lj;
            float p3 = b1[c];
            #pragma unroll
            for (int t9 = 0; t9 < 9; ++t9) p3 += lip[t9] * W1c[t9*512 + c];
            #pragma unroll
            for (int r = 0; r < 4; ++r)
                Up[(size_t)(n0 + lh*4 + r)*512 + c] = acc[nt][r] + p3;
        }
    } else {
        #pragma unroll
        for (int nt = 0; nt < 8; ++nt) {
            int c = w*128 + nt*16 + lj;
            uint2 pk = { cvt_pk_bf16(acc[nt][0], acc[nt][1]),
                         cvt_pk_bf16(acc[nt][2], acc[nt][3]) };
            *(uint2*)&VT[((size_t)g*512 + c)*32 + j0 + lh*4] = pk;
        }
    }
}

// fused edge pipeline: 2 src nodes per block, 5-phase double-buffered (c-blocks of 128)
// stage1 (swapped): ef1^T[c][m] = W1dT(A) x fd(B) + VT(A) x ind(B); +base, silu -> buf
// stage2: acc2[m][c2] += ef1(A from buf) x W2T(B)
// NOTE: no min-waves bound — acc2[4][8] (128 regs) must stay in the unified
// VGPR/AGPR file; (256,4) in round 4 forced a 64-VGPR cap and spilled ~2 GB
// of scratch per dispatch.
__global__ __launch_bounds__(256) void k_edge(
    const float* __restrict__ Up, const unsigned short* __restrict__ VT,
    const float* __restrict__ frac,
    const unsigned short* __restrict__ W1dT,
    const unsigned short* __restrict__ W2T, const float* __restrict__ b2,
    float* __restrict__ agg)
{
    __shared__ __align__(16) unsigned short buf[2][64*128];
    int n0 = blockIdx.x * 2, g = n0 >> 5, tid = threadIdx.x;
    int w = tid >> 6, l = tid & 63, lj = l & 15, lh = l >> 4;
    const unsigned short* VTg = VT + (size_t)g*512*32;

    // per-lane frac diffs: h = src offset (0/1), dd = dst half (m&16)
    float di[2][2][3];
    #pragma unroll
    for (int h = 0; h < 2; ++h)
        #pragma unroll
        for (int dd = 0; dd < 2; ++dd) {
            int dstn = g*32 + dd*16 + lj, srcn = n0 + h;
            #pragma unroll
            for (int comp = 0; comp < 3; ++comp) {
                float d = frac[dstn*3 + comp] - frac[srcn*3 + comp];
                d -= floorf(d);
                di[h][dd][comp] = d;
            }
        }
    // fd B-fragments in registers: fdf[kt][mt][kk] = fd[mt*16+lj][kt*32+lh*8+kk]
    bf16x8 fdf[2][4];
    #pragma unroll
    for (int kt = 0; kt < 2; ++kt)
        #pragma unroll
        for (int mt = 0; mt < 4; ++mt) {
            int h = mt >> 1, dd = mt & 1;
            #pragma unroll
            for (int kk = 0; kk < 8; ++kk) {
                int k = kt*32 + lh*8 + kk;
                float val = 0.f;
                if (k < 60) {
                    int isCos = k >= 30;
                    int dq = k - (isCos ? 30 : 0);
                    int comp = dq >= 20 ? 2 : (dq >= 10 ? 1 : 0);
                    int f = dq - comp*10;
                    float u = di[h][dd][comp] * (float)f;
                    u -= floorf(u);
                    val = isCos ? __builtin_amdgcn_cosf(u) : __builtin_amdgcn_sinf(u);
                }
                fdf[kt][mt][kk] = (short)f2bf(val);
            }
        }
    // indicator B-frags for V-gather: ind[dd][kk] = (lh*8+kk == dd*16+lj)
    bf16x8 ind[2];
    #pragma unroll
    for (int dd = 0; dd < 2; ++dd)
        #pragma unroll
        for (int kk = 0; kk < 8; ++kk)
            ind[dd][kk] = (short)((lh*8 + kk == dd*16 + lj) ? 0x3F80 : 0);

    f32x4 acc2[4][8];
    #pragma unroll
    for (int mt = 0; mt < 4; ++mt)
        #pragma unroll
        for (int nt = 0; nt < 8; ++nt) acc2[mt][nt] = (f32x4){0.f,0.f,0.f,0.f};

    for (int p = 0; p < 5; ++p) {
        if (p < 4) {
            f32x4 a1[2][4];
            #pragma unroll
            for (int q = 0; q < 2; ++q)
                #pragma unroll
                for (int mt = 0; mt < 4; ++mt) a1[q][mt] = (f32x4){0.f,0.f,0.f,0.f};
            #pragma unroll
            for (int q = 0; q < 2; ++q) {
                int crow = p*128 + (w*2+q)*16 + lj;
                bf16x8 vf = *(const bf16x8*)&VTg[(size_t)crow*32 + lh*8];
                #pragma unroll
                for (int mt = 0; mt < 4; ++mt)
                    a1[q][mt] = __builtin_amdgcn_mfma_f32_16x16x32_bf16(vf, ind[mt&1], a1[q][mt], 0, 0, 0);
                #pragma unroll
                for (int kt = 0; kt < 2; ++kt) {
                    bf16x8 wf = *(const bf16x8*)&W1dT[(size_t)crow*64 + kt*32 + lh*8];
                    #pragma unroll
                    for (int mt = 0; mt < 4; ++mt)
                        a1[q][mt] = __builtin_amdgcn_mfma_f32_16x16x32_bf16(wf, fdf[kt][mt], a1[q][mt], 0, 0, 0);
                }
            }
            unsigned short* bdst = &buf[p&1][0];
            #pragma unroll
            for (int q = 0; q < 2; ++q) {
                int c0l = (w*2+q)*16 + lh*4;
                float4 bs0 = *(const float4*)&Up[(size_t)n0*512 + p*128 + c0l];
                float4 bs1 = *(const float4*)&Up[(size_t)(n0+1)*512 + p*128 + c0l];
                #pragma unroll
                for (int mt = 0; mt < 4; ++mt) {
                    float4 bb = (mt >> 1) ? bs1 : bs0;
                    float x0 = silu_f(a1[q][mt][0] + bb.x);
                    float x1 = silu_f(a1[q][mt][1] + bb.y);
                    float x2 = silu_f(a1[q][mt][2] + bb.z);
                    float x3 = silu_f(a1[q][mt][3] + bb.w);
                    uint2 pk = { cvt_pk_bf16(x0, x1), cvt_pk_bf16(x2, x3) };
                    int m = mt*16 + lj;
                    *(uint2*)&bdst[m*128 + (c0l ^ ((lj&7)<<3))] = pk;
                }
            }
        }
        if (p > 0) {
            int pp = p - 1;
            const unsigned short* bsrc = &buf[pp&1][0];
            #pragma unroll
            for (int kt = 0; kt < 4; ++kt) {
                bf16x8 af[4];
                #pragma unroll
                for (int mt = 0; mt < 4; ++mt)
                    af[mt] = *(const bf16x8*)&bsrc[(mt*16+lj)*128 + ((kt*32+lh*8) ^ ((lj&7)<<3))];
                #pragma unroll
                for (int nt = 0; nt < 8; ++nt) {
                    int c2 = w*128 + nt*16 + lj;
                    bf16x8 bfr = *(const bf16x8*)&W2T[(size_t)c2*512 + pp*128 + kt*32 + lh*8];
                    #pragma unroll
                    for (int mt = 0; mt < 4; ++mt)
                        acc2[mt][nt] = __builtin_amdgcn_mfma_f32_16x16x32_bf16(af[mt], bfr, acc2[mt][nt], 0, 0, 0);
                }
            }
        }
        if (p < 4) __syncthreads();
    }

    // epilogue: silu + per-node column mean
    #pragma unroll
    for (int nt = 0; nt < 8; ++nt) {
        int c = w*128 + nt*16 + lj;
        float bv = b2[c];
        float s0 = 0.f, s1 = 0.f;
        #pragma unroll
        for (int mt = 0; mt < 4; ++mt)
            #pragma unroll
            for (int r = 0; r < 4; ++r) {
                float x = silu_f(acc2[mt][nt][r] + bv);
                if (mt < 2) s0 += x; else s1 += x;
            }
        s0 += __shfl_xor(s0, 16); s0 += __shfl_xor(s0, 32);
        s1 += __shfl_xor(s1, 16); s1 += __shfl_xor(s1, 32);
        if (lh == 0) {
            agg[(size_t)n0*512 + c]     = s0 * (1.0f/32.0f);
            agg[(size_t)(n0+1)*512 + c] = s1 * (1.0f/32.0f);
        }
    }
}

// h1 = silu([nf,agg]@nW1 + b1) -> bf16 global ; 16 rows x 256 cols, 256 blocks
__global__ __launch_bounds__(256) void k_node1(
    const float* __restrict__ nf, const float* __restrict__ agg,
    const unsigned short* __restrict__ W1T, const float* __restrict__ b1,
    unsigned short* __restrict__ h1g)
{
    __shared__ __align__(16) unsigned short nin_s[16*1024];
    int n0 = (blockIdx.x >> 1) * 16, half = blockIdx.x & 1, tid = threadIdx.x;
    for (int idx = tid; idx < 16*256; idx += 256) {
        int m = idx >> 8, q = idx & 255;
        int k4 = q * 4;
        float4 v = (k4 < 512) ? *(const float4*)&nf[(size_t)(n0+m)*512 + k4]
                              : *(const float4*)&agg[(size_t)(n0+m)*512 + (k4-512)];
        uint2 pk = { cvt_pk_bf16(v.x, v.y), cvt_pk_bf16(v.z, v.w) };
        *(uint2*)&nin_s[m*1024 + (k4 ^ ((m&7)<<3))] = pk;
    }
    __syncthreads();
    int w = tid >> 6, l = tid & 63, lj = l & 15, lh = l >> 4;
    f32x4 acc[4];
    #pragma unroll
    for (int nt = 0; nt < 4; ++nt) acc[nt] = (f32x4){0.f,0.f,0.f,0.f};
    for (int kt = 0; kt < 32; ++kt) {
        int k = kt*32 + lh*8;
        bf16x8 a = *(const bf16x8*)&nin_s[lj*1024 + (k ^ ((lj&7)<<3))];
        #pragma unroll
        for (int nt = 0; nt < 4; ++nt) {
            int c = half*256 + w*64 + nt*16 + lj;
            bf16x8 b = *(const bf16x8*)&W1T[(size_t)c*1024 + k];
            acc[nt] = __builtin_amdgcn_mfma_f32_16x16x32_bf16(a, b, acc[nt], 0, 0, 0);
        }
    }
    #pragma unroll
    for (int nt = 0; nt < 4; ++nt) {
        int c = half*256 + w*64 + nt*16 + lj;
        float bv = b1[c];
        #pragma unroll
        for (int r = 0; r < 4; ++r)
            h1g[(size_t)(n0 + lh*4 + r)*512 + c] = f2bf(silu_f(acc[nt][r] + bv));
    }
}

// nf += silu(h1@nW2 + b2) ; 16 rows x 256 cols, 256 blocks
__global__ __launch_bounds__(256) void k_node2(
    float* __restrict__ nf, const unsigned short* __restrict__ h1g,
    const unsigned short* __restrict__ W2T, const float* __restrict__ b2)
{
    __shared__ __align__(16) unsigned short h1_s[16*512];
    int n0 = (blockIdx.x >> 1) * 16, half = blockIdx.x & 1, tid = threadIdx.x;
    for (int idx = tid; idx < 16*64; idx += 256) {
        int m = idx >> 6, k8 = (idx & 63) * 8;
        bf16x8 v = *(const bf16x8*)&h1g[(size_t)(n0+m)*512 + k8];
        *(bf16x8*)&h1_s[m*512 + (k8 ^ ((m&7)<<3))] = v;
    }
    __syncthreads();
    int w = tid >> 6, l = tid & 63, lj = l & 15, lh = l >> 4;
    f32x4 acc[4];
    #pragma unroll
    for (int nt = 0; nt < 4; ++nt) acc[nt] = (f32x4){0.f,0.f,0.f,0.f};
    for (int kt = 0; kt < 16; ++kt) {
        int k = kt*32 + lh*8;
        bf16x8 a = *(const bf16x8*)&h1_s[lj*512 + (k ^ ((lj&7)<<3))];
        #pragma unroll
        for (int nt = 0; nt < 4; ++nt) {
            int c = half*256 + w*64 + nt*16 + lj;
            bf16x8 b = *(const bf16x8*)&W2T[(size_t)c*512 + k];
            acc[nt] = __builtin_amdgcn_mfma_f32_16x16x32_bf16(a, b, acc[nt], 0, 0, 0);
        }
    }
    #pragma unroll
    for (int nt = 0; nt < 4; ++nt) {
        int c = half*256 + w*64 + nt*16 + lj;
        float bv = b2[c];
        #pragma unroll
        for (int r = 0; r < 4; ++r) {
            size_t o = (size_t)(n0 + lh*4 + r)*512 + c;
            nf[o] = nf[o] + silu_f(acc[nt][r] + bv);
        }
    }
}

__global__ __launch_bounds__(256) void k_coord(const float* __restrict__ nf,
                                               const float* __restrict__ cW,
                                               float* __restrict__ out) {
    int gid = blockIdx.x * 256 + threadIdx.x;
    if (gid >= 2048 * 3) return;
    int n = gid / 3, c = gid - n * 3;
    float s = 0.f;
    for (int k = 0; k < 512; ++k) s += nf[n * 512 + k] * cW[k * 3 + c];
    out[576 + gid] = s;
}

__global__ __launch_bounds__(256) void k_graph(const float* __restrict__ nf,
                                               const float* __restrict__ lW,
                                               const float* __restrict__ lat,
                                               float* __restrict__ out) {
    __shared__ float gf[512];
    __shared__ float lo9[9];
    int b = blockIdx.x, tid = threadIdx.x;
    float s0 = 0.f, s1 = 0.f;
    for (int r = 0; r < 32; ++r) {
        s0 += nf[(b * 32 + r) * 512 + tid];
        s1 += nf[(b * 32 + r) * 512 + tid + 256];
    }
    gf[tid]       = s0 * (1.f / 32.f);
    gf[tid + 256] = s1 * (1.f / 32.f);
    __syncthreads();
    if (tid < 9) {
        float s = 0.f;
        for (int k = 0; k < 512; ++k) s += gf[k] * lW[k * 9 + tid];
        lo9[tid] = s;
    }
    __syncthreads();
    if (tid < 9) {
        int i = tid / 3, kk = tid - (tid / 3) * 3;
        float s = lo9[i*3+0] * lat[b*9 + 0*3 + kk]
                + lo9[i*3+1] * lat[b*9 + 1*3 + kk]
                + lo9[i*3+2] * lat[b*9 + 2*3 + kk];
        out[b * 9 + tid] = s;
    }
}

extern "C" void kernel_launch(void* const* d_in, const int* in_sizes, int n_in,
                              void* d_out, int out_size, void* d_ws, size_t ws_size,
                              hipStream_t stream)
{
    const float* t    = (const float*)d_in[0];
    const float* frac = (const float*)d_in[1];
    const float* lat  = (const float*)d_in[2];
    const float* emb  = (const float*)d_in[3];
    const float* Wl   = (const float*)d_in[4];
    const float* bl   = (const float*)d_in[5];
    const float* eW1  = (const float*)d_in[6];
    const float* eb1  = (const float*)d_in[7];
    const float* eW2  = (const float*)d_in[8];
    const float* eb2  = (const float*)d_in[9];
    const float* nW1  = (const float*)d_in[10];
    const float* nb1  = (const float*)d_in[11];
    const float* nW2  = (const float*)d_in[12];
    const float* nb2  = (const float*)d_in[13];
    const float* cW   = (const float*)d_in[14];
    const float* lW   = (const float*)d_in[15];
    const int* atom_types = (const int*)d_in[16];

    float* out  = (float*)d_out;
    float* wsf  = (float*)d_ws;
    float* nf   = wsf + NF_OFF;
    float* Uagg = wsf + UAGG_OFF;   // U' during k_uv/k_edge, then agg (row-exclusive)
    unsigned short* VT  = (unsigned short*)(wsf + VT_OFF);
    unsigned short* h1g = (unsigned short*)(wsf + H1_OFF);
    unsigned short* wbf = (unsigned short*)(wsf + WBF_OFF);

    k_prep<<<384 + 4*1568, 256, 0, stream>>>(Wl, eW1, eW2, nW1, nW2, wbf);
    k_init<<<256, 256, 0, stream>>>(t, emb, wbf, bl, atom_types, nf);
    for (int l = 0; l < 4; ++l) {
        const unsigned short* uvT  = wbf + SZ_INITT + (size_t)l * SZ_LAYER;
        const unsigned short* w1dT = uvT + SZ_UVT;
        const unsigned short* w2T  = w1dT + SZ_W1DT;
        const unsigned short* nw1T = w2T + SZ_W2T;
        const unsigned short* nw2T = nw1T + SZ_NW1T;
        k_uv<<<256, 256, 0, stream>>>(nf, uvT, lat,
                                      eW1 + (size_t)l*1093*512 + 1024*512,
                                      eb1 + l*512, Uagg, VT);
        k_edge<<<1024, 256, 0, stream>>>(Uagg, VT, frac, w1dT, w2T, eb2 + l*512, Uagg);
        k_node1<<<256, 256, 0, stream>>>(nf, Uagg, nw1T, nb1 + l*512, h1g);
        k_node2<<<256, 256, 0, stream>>>(nf, h1g, nw2T, nb2 + l*512);
    }
    k_coord<<<24, 256, 0, stream>>>(nf, cW, out);
    k_graph<<<64, 256, 0, stream>>>(nf, lW, lat, out);
}

// Round 6
// 898.463 us; speedup vs baseline: 2.8496x; 1.0605x over previous
//
#include <hip/hip_runtime.h>
#include <math.h>

// B=64 graphs, A=32 atoms, N=2048 nodes, E=65536 edges, H=512, LAT=256, L=4, DIS=60, EIN=1093

typedef short bf16x8 __attribute__((ext_vector_type(8)));
typedef float f32x4 __attribute__((ext_vector_type(4)));

__device__ __forceinline__ float silu_f(float x) {
    float e = __builtin_amdgcn_exp2f(x * -1.44269504088896f);
    return x * __builtin_amdgcn_rcpf(1.0f + e);
}
__device__ __forceinline__ unsigned short f2bf(float x) {
    unsigned int u = __float_as_uint(x);
    u += 0x7fffu + ((u >> 16) & 1u);
    return (unsigned short)(u >> 16);
}
__device__ __forceinline__ unsigned int cvt_pk_bf16(float lo, float hi) {
    unsigned int r;
    asm("v_cvt_pk_bf16_f32 %0, %1, %2" : "=v"(r) : "v"(lo), "v"(hi));
    return r;
}

// ---- workspace layout (float offsets) ----
#define NF_OFF    0
#define UAGG_OFF  (2048*512)
#define VT_OFF    (2*2048*512)                 // ushort region 64*512*32 = 524288 floats
#define H1_OFF    (VT_OFF + 524288)            // ushort region 2048*512  = 524288 floats
#define WBF_OFF   (H1_OFF + 524288)
// bf16 weight region sizes (ushort elements)
#define SZ_INITT (512*768)
#define SZ_UVT   (1024*512)
#define SZ_W1DT  (512*64)
#define SZ_W2T   (512*512)
#define SZ_NW1T  (512*1024)
#define SZ_NW2T  (512*512)
#define SZ_LAYER (SZ_UVT+SZ_W1DT+SZ_W2T+SZ_NW1T+SZ_NW2T)

// ---- weight transpose+convert: f32 [K][512] -> bf16 [512 n][Kd k] ----
__global__ __launch_bounds__(256) void k_prep(
    const float* __restrict__ Wl, const float* __restrict__ eW1,
    const float* __restrict__ eW2, const float* __restrict__ nW1,
    const float* __restrict__ nW2, unsigned short* __restrict__ wbf)
{
    __shared__ float tile[32][33];
    int bid = blockIdx.x;
    const float* src; int K; unsigned short* dst; int Kd; int t;
    if (bid < 384) { src = Wl; K = 768; dst = wbf; Kd = 768; t = bid; }
    else {
        int b = bid - 384; int l = b / 1568; int j = b - l * 1568;
        const float* e1 = eW1 + (size_t)l * 1093 * 512;
        unsigned short* base = wbf + SZ_INITT + (size_t)l * SZ_LAYER;
        if (j < 256)      { src = e1;                       K = 512;  dst = base;                                   Kd = 512;  t = j; }
        else if (j < 512) { src = e1 + 512*512;             K = 512;  dst = base + 512*512;                         Kd = 512;  t = j-256; }
        else if (j < 544) { src = e1 + 1033*512;            K = 60;   dst = base + SZ_UVT;                          Kd = 64;   t = j-512; }
        else if (j < 800) { src = eW2 + (size_t)l*512*512;  K = 512;  dst = base + SZ_UVT+SZ_W1DT;                  Kd = 512;  t = j-544; }
        else if (j <1312) { src = nW1 + (size_t)l*1024*512; K = 1024; dst = base + SZ_UVT+SZ_W1DT+SZ_W2T;           Kd = 1024; t = j-800; }
        else              { src = nW2 + (size_t)l*512*512;  K = 512;  dst = base + SZ_UVT+SZ_W1DT+SZ_W2T+SZ_NW1T;   Kd = 512;  t = j-1312; }
    }
    int tr = t >> 4, tc = t & 15;
    int k0 = tr * 32, nn0 = tc * 32;
    int r8 = threadIdx.x >> 5, cc = threadIdx.x & 31;
    #pragma unroll
    for (int rr = 0; rr < 4; ++rr) {
        int row = rr*8 + r8;
        int k = k0 + row;
        tile[row][cc] = (k < K) ? src[(size_t)k*512 + nn0 + cc] : 0.f;
    }
    __syncthreads();
    #pragma unroll
    for (int rr = 0; rr < 4; ++rr) {
        int row = rr*8 + r8;
        dst[(size_t)(nn0+row)*Kd + k0 + cc] = f2bf(tile[cc][row]);
    }
}

// nf0 = concat(emb,t)@Wl + bl : 16 rows x 256 cols per block, 256 blocks
__global__ __launch_bounds__(256) void k_init(
    const float* __restrict__ tvec, const float* __restrict__ emb,
    const unsigned short* __restrict__ WT, const float* __restrict__ bl,
    const int* __restrict__ atom_types, float* __restrict__ nf)
{
    __shared__ __align__(16) unsigned short cat_s[16*768];
    int n0 = (blockIdx.x >> 1) * 16, half = blockIdx.x & 1, tid = threadIdx.x;
    for (int idx = tid; idx < 16*192; idx += 256) {
        int m = idx / 192, q = idx - m * 192;
        int k4 = q * 4, n = n0 + m;
        float4 v;
        if (k4 < 512) v = *(const float4*)&emb[(size_t)(atom_types[n]-1)*512 + k4];
        else          v = *(const float4*)&tvec[(size_t)(n>>5)*256 + (k4-512)];
        uint2 pk = { cvt_pk_bf16(v.x, v.y), cvt_pk_bf16(v.z, v.w) };
        *(uint2*)&cat_s[m*768 + (k4 ^ ((m&7)<<3))] = pk;
    }
    __syncthreads();
    int w = tid >> 6, l = tid & 63, lj = l & 15, lh = l >> 4;
    f32x4 acc[4];
    #pragma unroll
    for (int nt = 0; nt < 4; ++nt) acc[nt] = (f32x4){0.f,0.f,0.f,0.f};
    for (int kt = 0; kt < 24; ++kt) {
        int k = kt*32 + lh*8;
        bf16x8 a = *(const bf16x8*)&cat_s[lj*768 + (k ^ ((lj&7)<<3))];
        #pragma unroll
        for (int nt = 0; nt < 4; ++nt) {
            int c = half*256 + w*64 + nt*16 + lj;
            bf16x8 b = *(const bf16x8*)&WT[(size_t)c*768 + k];
            acc[nt] = __builtin_amdgcn_mfma_f32_16x16x32_bf16(a, b, acc[nt], 0, 0, 0);
        }
    }
    #pragma unroll
    for (int nt = 0; nt < 4; ++nt) {
        int c = half*256 + w*64 + nt*16 + lj;
        float bv = bl[c];
        #pragma unroll
        for (int r = 0; r < 4; ++r)
            nf[(size_t)(n0 + lh*4 + r)*512 + c] = acc[nt][r] + bv;
    }
}

// half0: U' = nf@W1a + latip@W1c + b1 (f32); half1: VT[g][c][j] = bf16(nf@W1b)
__global__ __launch_bounds__(256) void k_uv(
    const float* __restrict__ nf, const unsigned short* __restrict__ WT,
    const float* __restrict__ lat, const float* __restrict__ W1c,
    const float* __restrict__ b1, float* __restrict__ Up,
    unsigned short* __restrict__ VT)
{
    __shared__ __align__(16) unsigned short a_s[16*512];
    int n0 = (blockIdx.x >> 1) * 16, half = blockIdx.x & 1;
    int g = n0 >> 5, j0 = n0 & 31, tid = threadIdx.x;
    for (int idx = tid; idx < 16*128; idx += 256) {
        int m = idx >> 7, q = idx & 127;
        int k4 = q * 4;
        float4 v = *(const float4*)&nf[(size_t)(n0+m)*512 + k4];
        uint2 pk = { cvt_pk_bf16(v.x, v.y), cvt_pk_bf16(v.z, v.w) };
        *(uint2*)&a_s[m*512 + (k4 ^ ((m&7)<<3))] = pk;
    }
    __syncthreads();
    int w = tid >> 6, l = tid & 63, lj = l & 15, lh = l >> 4;
    const unsigned short* Wh = WT + (size_t)half*512*512;
    f32x4 acc[8];
    #pragma unroll
    for (int nt = 0; nt < 8; ++nt) acc[nt] = (f32x4){0.f,0.f,0.f,0.f};
    for (int kt = 0; kt < 16; ++kt) {
        int k = kt*32 + lh*8;
        bf16x8 a = *(const bf16x8*)&a_s[lj*512 + (k ^ ((lj&7)<<3))];
        #pragma unroll
        for (int nt = 0; nt < 8; ++nt) {
            int c = w*128 + nt*16 + lj;
            bf16x8 b = *(const bf16x8*)&Wh[(size_t)c*512 + k];
            acc[nt] = __builtin_amdgcn_mfma_f32_16x16x32_bf16(a, b, acc[nt], 0, 0, 0);
        }
    }
    if (half == 0) {
        float L[9], lip[9];
        #pragma unroll
        for (int i = 0; i < 9; ++i) L[i] = lat[g*9 + i];
        #pragma unroll
        for (int i = 0; i < 3; ++i)
            #pragma unroll
            for (int kk = 0; kk < 3; ++kk)
                lip[i*3+kk] = L[i*3]*L[kk*3] + L[i*3+1]*L[kk*3+1] + L[i*3+2]*L[kk*3+2];
        #pragma unroll
        for (int nt = 0; nt < 8; ++nt) {
            int c = w*128 + nt*16 + lj;
            float p3 = b1[c];
            #pragma unroll
            for (int t9 = 0; t9 < 9; ++t9) p3 += lip[t9] * W1c[t9*512 + c];
            #pragma unroll
            for (int r = 0; r < 4; ++r)
                Up[(size_t)(n0 + lh*4 + r)*512 + c] = acc[nt][r] + p3;
        }
    } else {
        #pragma unroll
        for (int nt = 0; nt < 8; ++nt) {
            int c = w*128 + nt*16 + lj;
            uint2 pk = { cvt_pk_bf16(acc[nt][0], acc[nt][1]),
                         cvt_pk_bf16(acc[nt][2], acc[nt][3]) };
            *(uint2*)&VT[((size_t)g*512 + c)*32 + j0 + lh*4] = pk;
        }
    }
}

// fused edge pipeline: ONE src node per block (32 edge rows), 256 threads, 2048 blocks.
// stage1 (swapped): ef1^T[c][m] = W1dT x fd + VT x ind ; +U', silu -> 32KB LDS
// stage2: acc2[m 2][c2 8] += ef1 x W2T ; silu ; column-mean over 32 rows.
// Register budget is the design driver: acc1 live = 8 regs (per-q epilogue),
// acc2 = 64 regs, so ~3 waves/SIMD + 32KB LDS -> 3-4 blocks/CU of
// independently-barriered blocks (r5's 220-VGPR/acc128 design got 1 wave/SIMD).
__global__ __launch_bounds__(256) void k_edge(
    const float* __restrict__ Up, const unsigned short* __restrict__ VT,
    const float* __restrict__ frac,
    const unsigned short* __restrict__ W1dT,
    const unsigned short* __restrict__ W2T, const float* __restrict__ b2,
    float* __restrict__ agg)
{
    __shared__ __align__(16) unsigned short ef1_s[32*512];
    int n0 = blockIdx.x, g = n0 >> 5, tid = threadIdx.x;
    int wid = tid >> 6, l = tid & 63, lj = l & 15, lh = l >> 4;
    const unsigned short* VTg = VT + (size_t)g*512*32;

    // stage 1: this wave computes ef1 cols [wid*128, wid*128+128)
    {
        // per-lane frac diffs: dd = dst half (m>=16)
        float di[2][3];
        #pragma unroll
        for (int dd = 0; dd < 2; ++dd) {
            int dstn = g*32 + dd*16 + lj;
            #pragma unroll
            for (int comp = 0; comp < 3; ++comp) {
                float d = frac[dstn*3 + comp] - frac[n0*3 + comp];
                d -= floorf(d);
                di[dd][comp] = d;
            }
        }
        // fd B-fragments: fdf[kt][mt][kk] = fd[mt*16+lj][kt*32+lh*8+kk]
        bf16x8 fdf[2][2];
        #pragma unroll
        for (int kt = 0; kt < 2; ++kt)
            #pragma unroll
            for (int mt = 0; mt < 2; ++mt) {
                #pragma unroll
                for (int kk = 0; kk < 8; ++kk) {
                    int k = kt*32 + lh*8 + kk;
                    float val = 0.f;
                    if (k < 60) {
                        int isCos = k >= 30;
                        int dq = k - (isCos ? 30 : 0);
                        int comp = dq >= 20 ? 2 : (dq >= 10 ? 1 : 0);
                        int f = dq - comp*10;
                        float u = di[mt][comp] * (float)f;
                        u -= floorf(u);
                        val = isCos ? __builtin_amdgcn_cosf(u) : __builtin_amdgcn_sinf(u);
                    }
                    fdf[kt][mt][kk] = (short)f2bf(val);
                }
            }
        // indicator B-frags: ind[mt][kk] = (lh*8+kk == mt*16+lj)
        bf16x8 ind[2];
        #pragma unroll
        for (int mt = 0; mt < 2; ++mt)
            #pragma unroll
            for (int kk = 0; kk < 8; ++kk)
                ind[mt][kk] = (short)((lh*8 + kk == mt*16 + lj) ? 0x3F80 : 0);

        #pragma unroll
        for (int q = 0; q < 8; ++q) {
            int crow = wid*128 + q*16 + lj;
            f32x4 a1[2];
            a1[0] = (f32x4){0.f,0.f,0.f,0.f};
            a1[1] = (f32x4){0.f,0.f,0.f,0.f};
            bf16x8 vf = *(const bf16x8*)&VTg[(size_t)crow*32 + lh*8];
            #pragma unroll
            for (int mt = 0; mt < 2; ++mt)
                a1[mt] = __builtin_amdgcn_mfma_f32_16x16x32_bf16(vf, ind[mt], a1[mt], 0, 0, 0);
            #pragma unroll
            for (int kt = 0; kt < 2; ++kt) {
                bf16x8 wf = *(const bf16x8*)&W1dT[(size_t)crow*64 + kt*32 + lh*8];
                #pragma unroll
                for (int mt = 0; mt < 2; ++mt)
                    a1[mt] = __builtin_amdgcn_mfma_f32_16x16x32_bf16(wf, fdf[kt][mt], a1[mt], 0, 0, 0);
            }
            // epilogue for this q-tile: + U'[n0], silu, bf16 -> LDS (ef1^T -> ef1)
            int c0 = wid*128 + q*16 + lh*4;
            float4 bs = *(const float4*)&Up[(size_t)n0*512 + c0];
            #pragma unroll
            for (int mt = 0; mt < 2; ++mt) {
                int m = mt*16 + lj;
                float x0 = silu_f(a1[mt][0] + bs.x);
                float x1 = silu_f(a1[mt][1] + bs.y);
                float x2 = silu_f(a1[mt][2] + bs.z);
                float x3 = silu_f(a1[mt][3] + bs.w);
                uint2 pk = { cvt_pk_bf16(x0, x1), cvt_pk_bf16(x2, x3) };
                *(uint2*)&ef1_s[m*512 + (c0 ^ ((m&7)<<3))] = pk;
            }
        }
    }
    __syncthreads();

    // stage 2: ef1[32,512] @ W2T cols [wid*128, +128), then silu + row-group mean
    f32x4 acc2[2][8];
    #pragma unroll
    for (int mt = 0; mt < 2; ++mt)
        #pragma unroll
        for (int nt = 0; nt < 8; ++nt) acc2[mt][nt] = (f32x4){0.f,0.f,0.f,0.f};
    for (int kt = 0; kt < 16; ++kt) {
        int k = kt*32 + lh*8;
        bf16x8 af[2];
        #pragma unroll
        for (int mt = 0; mt < 2; ++mt)
            af[mt] = *(const bf16x8*)&ef1_s[(mt*16+lj)*512 + (k ^ ((lj&7)<<3))];
        #pragma unroll
        for (int nt = 0; nt < 8; ++nt) {
            int c2 = wid*128 + nt*16 + lj;
            bf16x8 bfr = *(const bf16x8*)&W2T[(size_t)c2*512 + k];
            #pragma unroll
            for (int mt = 0; mt < 2; ++mt)
                acc2[mt][nt] = __builtin_amdgcn_mfma_f32_16x16x32_bf16(af[mt], bfr, acc2[mt][nt], 0, 0, 0);
        }
    }
    #pragma unroll
    for (int nt = 0; nt < 8; ++nt) {
        int c = wid*128 + nt*16 + lj;
        float bv = b2[c];
        float s = 0.f;
        #pragma unroll
        for (int mt = 0; mt < 2; ++mt)
            #pragma unroll
            for (int r = 0; r < 4; ++r)
                s += silu_f(acc2[mt][nt][r] + bv);
        s += __shfl_xor(s, 16);
        s += __shfl_xor(s, 32);
        if (lh == 0)
            agg[(size_t)n0*512 + c] = s * (1.0f/32.0f);
    }
}

// h1 = silu([nf,agg]@nW1 + b1) -> bf16 global ; 16 rows x 256 cols, 256 blocks
__global__ __launch_bounds__(256) void k_node1(
    const float* __restrict__ nf, const float* __restrict__ agg,
    const unsigned short* __restrict__ W1T, const float* __restrict__ b1,
    unsigned short* __restrict__ h1g)
{
    __shared__ __align__(16) unsigned short nin_s[16*1024];
    int n0 = (blockIdx.x >> 1) * 16, half = blockIdx.x & 1, tid = threadIdx.x;
    for (int idx = tid; idx < 16*256; idx += 256) {
        int m = idx >> 8, q = idx & 255;
        int k4 = q * 4;
        float4 v = (k4 < 512) ? *(const float4*)&nf[(size_t)(n0+m)*512 + k4]
                              : *(const float4*)&agg[(size_t)(n0+m)*512 + (k4-512)];
        uint2 pk = { cvt_pk_bf16(v.x, v.y), cvt_pk_bf16(v.z, v.w) };
        *(uint2*)&nin_s[m*1024 + (k4 ^ ((m&7)<<3))] = pk;
    }
    __syncthreads();
    int w = tid >> 6, l = tid & 63, lj = l & 15, lh = l >> 4;
    f32x4 acc[4];
    #pragma unroll
    for (int nt = 0; nt < 4; ++nt) acc[nt] = (f32x4){0.f,0.f,0.f,0.f};
    for (int kt = 0; kt < 32; ++kt) {
        int k = kt*32 + lh*8;
        bf16x8 a = *(const bf16x8*)&nin_s[lj*1024 + (k ^ ((lj&7)<<3))];
        #pragma unroll
        for (int nt = 0; nt < 4; ++nt) {
            int c = half*256 + w*64 + nt*16 + lj;
            bf16x8 b = *(const bf16x8*)&W1T[(size_t)c*1024 + k];
            acc[nt] = __builtin_amdgcn_mfma_f32_16x16x32_bf16(a, b, acc[nt], 0, 0, 0);
        }
    }
    #pragma unroll
    for (int nt = 0; nt < 4; ++nt) {
        int c = half*256 + w*64 + nt*16 + lj;
        float bv = b1[c];
        #pragma unroll
        for (int r = 0; r < 4; ++r)
            h1g[(size_t)(n0 + lh*4 + r)*512 + c] = f2bf(silu_f(acc[nt][r] + bv));
    }
}

// nf += silu(h1@nW2 + b2) ; 16 rows x 256 cols, 256 blocks
__global__ __launch_bounds__(256) void k_node2(
    float* __restrict__ nf, const unsigned short* __restrict__ h1g,
    const unsigned short* __restrict__ W2T, const float* __restrict__ b2)
{
    __shared__ __align__(16) unsigned short h1_s[16*512];
    int n0 = (blockIdx.x >> 1) * 16, half = blockIdx.x & 1, tid = threadIdx.x;
    for (int idx = tid; idx < 16*64; idx += 256) {
        int m = idx >> 6, k8 = (idx & 63) * 8;
        bf16x8 v = *(const bf16x8*)&h1g[(size_t)(n0+m)*512 + k8];
        *(bf16x8*)&h1_s[m*512 + (k8 ^ ((m&7)<<3))] = v;
    }
    __syncthreads();
    int w = tid >> 6, l = tid & 63, lj = l & 15, lh = l >> 4;
    f32x4 acc[4];
    #pragma unroll
    for (int nt = 0; nt < 4; ++nt) acc[nt] = (f32x4){0.f,0.f,0.f,0.f};
    for (int kt = 0; kt < 16; ++kt) {
        int k = kt*32 + lh*8;
        bf16x8 a = *(const bf16x8*)&h1_s[lj*512 + (k ^ ((lj&7)<<3))];
        #pragma unroll
        for (int nt = 0; nt < 4; ++nt) {
            int c = half*256 + w*64 + nt*16 + lj;
            bf16x8 b = *(const bf16x8*)&W2T[(size_t)c*512 + k];
            acc[nt] = __builtin_amdgcn_mfma_f32_16x16x32_bf16(a, b, acc[nt], 0, 0, 0);
        }
    }
    #pragma unroll
    for (int nt = 0; nt < 4; ++nt) {
        int c = half*256 + w*64 + nt*16 + lj;
        float bv = b2[c];
        #pragma unroll
        for (int r = 0; r < 4; ++r) {
            size_t o = (size_t)(n0 + lh*4 + r)*512 + c;
            nf[o] = nf[o] + silu_f(acc[nt][r] + bv);
        }
    }
}

__global__ __launch_bounds__(256) void k_coord(const float* __restrict__ nf,
                                               const float* __restrict__ cW,
                                               float* __restrict__ out) {
    int gid = blockIdx.x * 256 + threadIdx.x;
    if (gid >= 2048 * 3) return;
    int n = gid / 3, c = gid - n * 3;
    float s = 0.f;
    for (int k = 0; k < 512; ++k) s += nf[n * 512 + k] * cW[k * 3 + c];
    out[576 + gid] = s;
}

__global__ __launch_bounds__(256) void k_graph(const float* __restrict__ nf,
                                               const float* __restrict__ lW,
                                               const float* __restrict__ lat,
                                               float* __restrict__ out) {
    __shared__ float gf[512];
    __shared__ float lo9[9];
    int b = blockIdx.x, tid = threadIdx.x;
    float s0 = 0.f, s1 = 0.f;
    for (int r = 0; r < 32; ++r) {
        s0 += nf[(b * 32 + r) * 512 + tid];
        s1 += nf[(b * 32 + r) * 512 + tid + 256];
    }
    gf[tid]       = s0 * (1.f / 32.f);
    gf[tid + 256] = s1 * (1.f / 32.f);
    __syncthreads();
    if (tid < 9) {
        float s = 0.f;
        for (int k = 0; k < 512; ++k) s += gf[k] * lW[k * 9 + tid];
        lo9[tid] = s;
    }
    __syncthreads();
    if (tid < 9) {
        int i = tid / 3, kk = tid - (tid / 3) * 3;
        float s = lo9[i*3+0] * lat[b*9 + 0*3 + kk]
                + lo9[i*3+1] * lat[b*9 + 1*3 + kk]
                + lo9[i*3+2] * lat[b*9 + 2*3 + kk];
        out[b * 9 + tid] = s;
    }
}

extern "C" void kernel_launch(void* const* d_in, const int* in_sizes, int n_in,
                              void* d_out, int out_size, void* d_ws, size_t ws_size,
                              hipStream_t stream)
{
    const float* t    = (const float*)d_in[0];
    const float* frac = (const float*)d_in[1];
    const float* lat  = (const float*)d_in[2];
    const float* emb  = (const float*)d_in[3];
    const float* Wl   = (const float*)d_in[4];
    const float* bl   = (const float*)d_in[5];
    const float* eW1  = (const float*)d_in[6];
    const float* eb1  = (const float*)d_in[7];
    const float* eW2  = (const float*)d_in[8];
    const float* eb2  = (const float*)d_in[9];
    const float* nW1  = (const float*)d_in[10];
    const float* nb1  = (const float*)d_in[11];
    const float* nW2  = (const float*)d_in[12];
    const float* nb2  = (const float*)d_in[13];
    const float* cW   = (const float*)d_in[14];
    const float* lW   = (const float*)d_in[15];
    const int* atom_types = (const int*)d_in[16];

    float* out  = (float*)d_out;
    float* wsf  = (float*)d_ws;
    float* nf   = wsf + NF_OFF;
    float* Uagg = wsf + UAGG_OFF;   // U' during k_uv/k_edge, then agg (row-exclusive)
    unsigned short* VT  = (unsigned short*)(wsf + VT_OFF);
    unsigned short* h1g = (unsigned short*)(wsf + H1_OFF);
    unsigned short* wbf = (unsigned short*)(wsf + WBF_OFF);

    k_prep<<<384 + 4*1568, 256, 0, stream>>>(Wl, eW1, eW2, nW1, nW2, wbf);
    k_init<<<256, 256, 0, stream>>>(t, emb, wbf, bl, atom_types, nf);
    for (int l = 0; l < 4; ++l) {
        const unsigned short* uvT  = wbf + SZ_INITT + (size_t)l * SZ_LAYER;
        const unsigned short* w1dT = uvT + SZ_UVT;
        const unsigned short* w2T  = w1dT + SZ_W1DT;
        const unsigned short* nw1T = w2T + SZ_W2T;
        const unsigned short* nw2T = nw1T + SZ_NW1T;
        k_uv<<<256, 256, 0, stream>>>(nf, uvT, lat,
                                      eW1 + (size_t)l*1093*512 + 1024*512,
                                      eb1 + l*512, Uagg, VT);
        k_edge<<<2048, 256, 0, stream>>>(Uagg, VT, frac, w1dT, w2T, eb2 + l*512, Uagg);
        k_node1<<<256, 256, 0, stream>>>(nf, Uagg, nw1T, nb1 + l*512, h1g);
        k_node2<<<256, 256, 0, stream>>>(nf, h1g, nw2T, nb2 + l*512);
    }
    k_coord<<<24, 256, 0, stream>>>(nf, cW, out);
    k_graph<<<64, 256, 0, stream>>>(nf, lW, lat, out);
}

// Round 7
// 692.964 us; speedup vs baseline: 3.6947x; 1.2966x over previous
//
#include <hip/hip_runtime.h>
#include <math.h>

// B=64 graphs, A=32 atoms, N=2048 nodes, E=65536 edges, H=512, LAT=256, L=4, DIS=60, EIN=1093

typedef short bf16x8 __attribute__((ext_vector_type(8)));
typedef float f32x4 __attribute__((ext_vector_type(4)));

__device__ __forceinline__ float silu_f(float x) {
    float e = __builtin_amdgcn_exp2f(x * -1.44269504088896f);
    return x * __builtin_amdgcn_rcpf(1.0f + e);
}
__device__ __forceinline__ unsigned short f2bf(float x) {
    unsigned int u = __float_as_uint(x);
    u += 0x7fffu + ((u >> 16) & 1u);
    return (unsigned short)(u >> 16);
}
__device__ __forceinline__ unsigned int cvt_pk_bf16(float lo, float hi) {
    unsigned int r;
    asm("v_cvt_pk_bf16_f32 %0, %1, %2" : "=v"(r) : "v"(lo), "v"(hi));
    return r;
}
// async global->LDS, 16B per lane; LDS dest must be wave-uniform base (+lane*16 implicit)
__device__ __forceinline__ void stage16(const unsigned short* g, unsigned short* l) {
    __builtin_amdgcn_global_load_lds(
        (const __attribute__((address_space(1))) unsigned int*)(g),
        (__attribute__((address_space(3))) unsigned int*)(l),
        16, 0, 0);
}

// ---- workspace layout (float offsets) ----
#define NF_OFF    0
#define UAGG_OFF  (2048*512)
#define VT_OFF    (2*2048*512)                 // ushort region 64*512*32 = 524288 floats
#define H1_OFF    (VT_OFF + 524288)            // ushort region 2048*512  = 524288 floats
#define WBF_OFF   (H1_OFF + 524288)
// bf16 weight region sizes (ushort elements)
#define SZ_INITT (512*768)
#define SZ_UVT   (1024*512)
#define SZ_W1DT  (512*64)
#define SZ_W2T   (512*512)
#define SZ_NW1T  (512*1024)
#define SZ_NW2T  (512*512)
#define SZ_LAYER (SZ_UVT+SZ_W1DT+SZ_W2T+SZ_NW1T+SZ_NW2T)

// ---- weight transpose+convert: f32 [K][512] -> bf16 [512 n][Kd k] ----
__global__ __launch_bounds__(256) void k_prep(
    const float* __restrict__ Wl, const float* __restrict__ eW1,
    const float* __restrict__ eW2, const float* __restrict__ nW1,
    const float* __restrict__ nW2, unsigned short* __restrict__ wbf)
{
    __shared__ float tile[32][33];
    int bid = blockIdx.x;
    const float* src; int K; unsigned short* dst; int Kd; int t;
    if (bid < 384) { src = Wl; K = 768; dst = wbf; Kd = 768; t = bid; }
    else {
        int b = bid - 384; int l = b / 1568; int j = b - l * 1568;
        const float* e1 = eW1 + (size_t)l * 1093 * 512;
        unsigned short* base = wbf + SZ_INITT + (size_t)l * SZ_LAYER;
        if (j < 256)      { src = e1;                       K = 512;  dst = base;                                   Kd = 512;  t = j; }
        else if (j < 512) { src = e1 + 512*512;             K = 512;  dst = base + 512*512;                         Kd = 512;  t = j-256; }
        else if (j < 544) { src = e1 + 1033*512;            K = 60;   dst = base + SZ_UVT;                          Kd = 64;   t = j-512; }
        else if (j < 800) { src = eW2 + (size_t)l*512*512;  K = 512;  dst = base + SZ_UVT+SZ_W1DT;                  Kd = 512;  t = j-544; }
        else if (j <1312) { src = nW1 + (size_t)l*1024*512; K = 1024; dst = base + SZ_UVT+SZ_W1DT+SZ_W2T;           Kd = 1024; t = j-800; }
        else              { src = nW2 + (size_t)l*512*512;  K = 512;  dst = base + SZ_UVT+SZ_W1DT+SZ_W2T+SZ_NW1T;   Kd = 512;  t = j-1312; }
    }
    int tr = t >> 4, tc = t & 15;
    int k0 = tr * 32, nn0 = tc * 32;
    int r8 = threadIdx.x >> 5, cc = threadIdx.x & 31;
    #pragma unroll
    for (int rr = 0; rr < 4; ++rr) {
        int row = rr*8 + r8;
        int k = k0 + row;
        tile[row][cc] = (k < K) ? src[(size_t)k*512 + nn0 + cc] : 0.f;
    }
    __syncthreads();
    #pragma unroll
    for (int rr = 0; rr < 4; ++rr) {
        int row = rr*8 + r8;
        dst[(size_t)(nn0+row)*Kd + k0 + cc] = f2bf(tile[cc][row]);
    }
}

// nf0 = concat(emb,t)@Wl + bl : 16 rows x 256 cols per block, 256 blocks
__global__ __launch_bounds__(256) void k_init(
    const float* __restrict__ tvec, const float* __restrict__ emb,
    const unsigned short* __restrict__ WT, const float* __restrict__ bl,
    const int* __restrict__ atom_types, float* __restrict__ nf)
{
    __shared__ __align__(16) unsigned short cat_s[16*768];
    int n0 = (blockIdx.x >> 1) * 16, half = blockIdx.x & 1, tid = threadIdx.x;
    for (int idx = tid; idx < 16*192; idx += 256) {
        int m = idx / 192, q = idx - m * 192;
        int k4 = q * 4, n = n0 + m;
        float4 v;
        if (k4 < 512) v = *(const float4*)&emb[(size_t)(atom_types[n]-1)*512 + k4];
        else          v = *(const float4*)&tvec[(size_t)(n>>5)*256 + (k4-512)];
        uint2 pk = { cvt_pk_bf16(v.x, v.y), cvt_pk_bf16(v.z, v.w) };
        *(uint2*)&cat_s[m*768 + (k4 ^ ((m&7)<<3))] = pk;
    }
    __syncthreads();
    int w = tid >> 6, l = tid & 63, lj = l & 15, lh = l >> 4;
    f32x4 acc[4];
    #pragma unroll
    for (int nt = 0; nt < 4; ++nt) acc[nt] = (f32x4){0.f,0.f,0.f,0.f};
    for (int kt = 0; kt < 24; ++kt) {
        int k = kt*32 + lh*8;
        bf16x8 a = *(const bf16x8*)&cat_s[lj*768 + (k ^ ((lj&7)<<3))];
        #pragma unroll
        for (int nt = 0; nt < 4; ++nt) {
            int c = half*256 + w*64 + nt*16 + lj;
            bf16x8 b = *(const bf16x8*)&WT[(size_t)c*768 + k];
            acc[nt] = __builtin_amdgcn_mfma_f32_16x16x32_bf16(a, b, acc[nt], 0, 0, 0);
        }
    }
    #pragma unroll
    for (int nt = 0; nt < 4; ++nt) {
        int c = half*256 + w*64 + nt*16 + lj;
        float bv = bl[c];
        #pragma unroll
        for (int r = 0; r < 4; ++r)
            nf[(size_t)(n0 + lh*4 + r)*512 + c] = acc[nt][r] + bv;
    }
}

// half0: U' = nf@W1a + latip@W1c + b1 (f32); half1: VT[g][c][j] = bf16(nf@W1b)
__global__ __launch_bounds__(256) void k_uv(
    const float* __restrict__ nf, const unsigned short* __restrict__ WT,
    const float* __restrict__ lat, const float* __restrict__ W1c,
    const float* __restrict__ b1, float* __restrict__ Up,
    unsigned short* __restrict__ VT)
{
    __shared__ __align__(16) unsigned short a_s[16*512];
    int n0 = (blockIdx.x >> 1) * 16, half = blockIdx.x & 1;
    int g = n0 >> 5, j0 = n0 & 31, tid = threadIdx.x;
    for (int idx = tid; idx < 16*128; idx += 256) {
        int m = idx >> 7, q = idx & 127;
        int k4 = q * 4;
        float4 v = *(const float4*)&nf[(size_t)(n0+m)*512 + k4];
        uint2 pk = { cvt_pk_bf16(v.x, v.y), cvt_pk_bf16(v.z, v.w) };
        *(uint2*)&a_s[m*512 + (k4 ^ ((m&7)<<3))] = pk;
    }
    __syncthreads();
    int w = tid >> 6, l = tid & 63, lj = l & 15, lh = l >> 4;
    const unsigned short* Wh = WT + (size_t)half*512*512;
    f32x4 acc[8];
    #pragma unroll
    for (int nt = 0; nt < 8; ++nt) acc[nt] = (f32x4){0.f,0.f,0.f,0.f};
    for (int kt = 0; kt < 16; ++kt) {
        int k = kt*32 + lh*8;
        bf16x8 a = *(const bf16x8*)&a_s[lj*512 + (k ^ ((lj&7)<<3))];
        #pragma unroll
        for (int nt = 0; nt < 8; ++nt) {
            int c = w*128 + nt*16 + lj;
            bf16x8 b = *(const bf16x8*)&Wh[(size_t)c*512 + k];
            acc[nt] = __builtin_amdgcn_mfma_f32_16x16x32_bf16(a, b, acc[nt], 0, 0, 0);
        }
    }
    if (half == 0) {
        float L[9], lip[9];
        #pragma unroll
        for (int i = 0; i < 9; ++i) L[i] = lat[g*9 + i];
        #pragma unroll
        for (int i = 0; i < 3; ++i)
            #pragma unroll
            for (int kk = 0; kk < 3; ++kk)
                lip[i*3+kk] = L[i*3]*L[kk*3] + L[i*3+1]*L[kk*3+1] + L[i*3+2]*L[kk*3+2];
        #pragma unroll
        for (int nt = 0; nt < 8; ++nt) {
            int c = w*128 + nt*16 + lj;
            float p3 = b1[c];
            #pragma unroll
            for (int t9 = 0; t9 < 9; ++t9) p3 += lip[t9] * W1c[t9*512 + c];
            #pragma unroll
            for (int r = 0; r < 4; ++r)
                Up[(size_t)(n0 + lh*4 + r)*512 + c] = acc[nt][r] + p3;
        }
    } else {
        #pragma unroll
        for (int nt = 0; nt < 8; ++nt) {
            int c = w*128 + nt*16 + lj;
            uint2 pk = { cvt_pk_bf16(acc[nt][0], acc[nt][1]),
                         cvt_pk_bf16(acc[nt][2], acc[nt][3]) };
            *(uint2*)&VT[((size_t)g*512 + c)*32 + j0 + lh*4] = pk;
        }
    }
}

// fused edge pipeline: 2 src nodes per block (M=64 edge rows), 512 threads (8 waves),
// grid 1024. Wave wid owns output cols [wid*64, +64).
// stage1 (swapped, r5-verified): ef1^T = W1dT x fd + VT x ind ; +U', silu -> ef1_s (64KB)
// stage2: W2T streamed through LDS in K=32 chunks (32KB x2, double-buffered,
//         global_load_lds w=16 with pre-swizzled source); B-frags via ds_read_b128.
// LDS total 128KB (dynamic). acc2[4][4]=64 AGPR; ~2 waves/SIMD.
__global__ __launch_bounds__(512) void k_edge(
    const float* __restrict__ Up, const unsigned short* __restrict__ VT,
    const float* __restrict__ frac,
    const unsigned short* __restrict__ W1dT,
    const unsigned short* __restrict__ W2T, const float* __restrict__ b2,
    float* __restrict__ agg)
{
    extern __shared__ __align__(16) unsigned short smem[];
    unsigned short* ef1_s = smem;            // [64][512] bf16 = 64KB
    unsigned short* w2s   = smem + 64*512;   // [2][512][32] bf16 = 64KB

    int n0 = blockIdx.x * 2, g = n0 >> 5, tid = threadIdx.x;
    int wid = tid >> 6, l = tid & 63, lj = l & 15, lh = l >> 4;
    const unsigned short* VTg = VT + (size_t)g*512*32;

    int lane_row = (l >> 2);        // 0..15
    int lane_s   = l & 3;           // 16B slot within 64B row
    // stage W2 chunk c (k in [c*32, c*32+32)) into buffer bsel.
    // LDS layout [512 c2][4 slots of 16B]; slot s holds global k-slot (s ^ (c2&3))
    // (inverse-swizzled source so swizzled ds_read is conflict-light).
    auto stageW2 = [&](int c, int bsel) {
        unsigned short* dstb = w2s + bsel*16384 + wid*512;   // wave-uniform
        #pragma unroll
        for (int i = 0; i < 4; ++i) {
            int row = i*128 + wid*16 + lane_row;
            const unsigned short* src =
                W2T + (size_t)row*512 + c*32 + ((lane_s ^ (row & 3)) << 3);
            stage16(src, dstb + i*4096);
        }
    };

    stageW2(0, 0);   // prefetch first chunk under stage-1 compute

    // ---------------- stage 1 ----------------
    {
        // per-lane frac diffs: h = src node offset, dd = dst half
        float di[2][2][3];
        #pragma unroll
        for (int h = 0; h < 2; ++h)
            #pragma unroll
            for (int dd = 0; dd < 2; ++dd) {
                int dstn = g*32 + dd*16 + lj;
                #pragma unroll
                for (int comp = 0; comp < 3; ++comp) {
                    float d = frac[dstn*3 + comp] - frac[(n0+h)*3 + comp];
                    d -= floorf(d);
                    di[h][dd][comp] = d;
                }
            }
        // fd B-fragments: fdf[kt][mt][kk] = fd[mt*16+lj][kt*32+lh*8+kk]
        bf16x8 fdf[2][4];
        #pragma unroll
        for (int kt = 0; kt < 2; ++kt)
            #pragma unroll
            for (int mt = 0; mt < 4; ++mt) {
                int h = mt >> 1, dd = mt & 1;
                #pragma unroll
                for (int kk = 0; kk < 8; ++kk) {
                    int k = kt*32 + lh*8 + kk;
                    float val = 0.f;
                    if (k < 60) {
                        int isCos = k >= 30;
                        int dq = k - (isCos ? 30 : 0);
                        int comp = dq >= 20 ? 2 : (dq >= 10 ? 1 : 0);
                        int f = dq - comp*10;
                        float u = di[h][dd][comp] * (float)f;
                        u -= floorf(u);
                        val = isCos ? __builtin_amdgcn_cosf(u) : __builtin_amdgcn_sinf(u);
                    }
                    fdf[kt][mt][kk] = (short)f2bf(val);
                }
            }
        // indicator B-frags: ind[dd][kk] = (lh*8+kk == dd*16+lj)
        bf16x8 ind[2];
        #pragma unroll
        for (int dd = 0; dd < 2; ++dd)
            #pragma unroll
            for (int kk = 0; kk < 8; ++kk)
                ind[dd][kk] = (short)((lh*8 + kk == dd*16 + lj) ? 0x3F80 : 0);

        #pragma unroll
        for (int q = 0; q < 4; ++q) {
            int crow = wid*64 + q*16 + lj;
            f32x4 a1[4];
            #pragma unroll
            for (int mt = 0; mt < 4; ++mt) a1[mt] = (f32x4){0.f,0.f,0.f,0.f};
            bf16x8 vf = *(const bf16x8*)&VTg[(size_t)crow*32 + lh*8];
            #pragma unroll
            for (int mt = 0; mt < 4; ++mt)
                a1[mt] = __builtin_amdgcn_mfma_f32_16x16x32_bf16(vf, ind[mt&1], a1[mt], 0, 0, 0);
            #pragma unroll
            for (int kt = 0; kt < 2; ++kt) {
                bf16x8 wf = *(const bf16x8*)&W1dT[(size_t)crow*64 + kt*32 + lh*8];
                #pragma unroll
                for (int mt = 0; mt < 4; ++mt)
                    a1[mt] = __builtin_amdgcn_mfma_f32_16x16x32_bf16(wf, fdf[kt][mt], a1[mt], 0, 0, 0);
            }
            // epilogue: + U', silu, bf16 -> ef1_s (transpose ef1^T -> ef1 rows)
            int c0 = wid*64 + q*16 + lh*4;
            float4 bs0 = *(const float4*)&Up[(size_t)n0*512 + c0];
            float4 bs1 = *(const float4*)&Up[(size_t)(n0+1)*512 + c0];
            #pragma unroll
            for (int mt = 0; mt < 4; ++mt) {
                float4 bb = (mt >> 1) ? bs1 : bs0;
                int m = mt*16 + lj;
                float x0 = silu_f(a1[mt][0] + bb.x);
                float x1 = silu_f(a1[mt][1] + bb.y);
                float x2 = silu_f(a1[mt][2] + bb.z);
                float x3 = silu_f(a1[mt][3] + bb.w);
                uint2 pk = { cvt_pk_bf16(x0, x1), cvt_pk_bf16(x2, x3) };
                *(uint2*)&ef1_s[m*512 + (c0 ^ ((m&7)<<3))] = pk;
            }
        }
    }
    __syncthreads();   // ef1 complete + chunk0 staged (vmcnt drained by barrier)

    // ---------------- stage 2 ----------------
    f32x4 acc2[4][4];
    #pragma unroll
    for (int mt = 0; mt < 4; ++mt)
        #pragma unroll
        for (int nt = 0; nt < 4; ++nt) acc2[mt][nt] = (f32x4){0.f,0.f,0.f,0.f};

    for (int c = 0; c < 16; ++c) {
        if (c < 15) stageW2(c + 1, (c + 1) & 1);
        const unsigned short* wb = w2s + (c & 1)*16384;
        int k = c*32 + lh*8;
        bf16x8 af[4];
        #pragma unroll
        for (int mt = 0; mt < 4; ++mt) {
            int m = mt*16 + lj;
            af[mt] = *(const bf16x8*)&ef1_s[m*512 + (k ^ ((m&7)<<3))];
        }
        #pragma unroll
        for (int nt = 0; nt < 4; ++nt) {
            int c2 = wid*64 + nt*16 + lj;
            bf16x8 bfr = *(const bf16x8*)&wb[c2*32 + ((lh*8) ^ ((c2&3)<<3))];
            #pragma unroll
            for (int mt = 0; mt < 4; ++mt)
                acc2[mt][nt] = __builtin_amdgcn_mfma_f32_16x16x32_bf16(af[mt], bfr, acc2[mt][nt], 0, 0, 0);
        }
        __syncthreads();  // chunk c consumed by all waves; chunk c+1 landed
    }

    // epilogue: silu + per-node column mean
    #pragma unroll
    for (int nt = 0; nt < 4; ++nt) {
        int cc = wid*64 + nt*16 + lj;
        float bv = b2[cc];
        float s0 = 0.f, s1 = 0.f;
        #pragma unroll
        for (int mt = 0; mt < 4; ++mt)
            #pragma unroll
            for (int r = 0; r < 4; ++r) {
                float x = silu_f(acc2[mt][nt][r] + bv);
                if (mt < 2) s0 += x; else s1 += x;
            }
        s0 += __shfl_xor(s0, 16); s0 += __shfl_xor(s0, 32);
        s1 += __shfl_xor(s1, 16); s1 += __shfl_xor(s1, 32);
        if (lh == 0) {
            agg[(size_t)n0*512 + cc]     = s0 * (1.0f/32.0f);
            agg[(size_t)(n0+1)*512 + cc] = s1 * (1.0f/32.0f);
        }
    }
}

// h1 = silu([nf,agg]@nW1 + b1) -> bf16 global ; 16 rows x 256 cols, 256 blocks
__global__ __launch_bounds__(256) void k_node1(
    const float* __restrict__ nf, const float* __restrict__ agg,
    const unsigned short* __restrict__ W1T, const float* __restrict__ b1,
    unsigned short* __restrict__ h1g)
{
    __shared__ __align__(16) unsigned short nin_s[16*1024];
    int n0 = (blockIdx.x >> 1) * 16, half = blockIdx.x & 1, tid = threadIdx.x;
    for (int idx = tid; idx < 16*256; idx += 256) {
        int m = idx >> 8, q = idx & 255;
        int k4 = q * 4;
        float4 v = (k4 < 512) ? *(const float4*)&nf[(size_t)(n0+m)*512 + k4]
                              : *(const float4*)&agg[(size_t)(n0+m)*512 + (k4-512)];
        uint2 pk = { cvt_pk_bf16(v.x, v.y), cvt_pk_bf16(v.z, v.w) };
        *(uint2*)&nin_s[m*1024 + (k4 ^ ((m&7)<<3))] = pk;
    }
    __syncthreads();
    int w = tid >> 6, l = tid & 63, lj = l & 15, lh = l >> 4;
    f32x4 acc[4];
    #pragma unroll
    for (int nt = 0; nt < 4; ++nt) acc[nt] = (f32x4){0.f,0.f,0.f,0.f};
    for (int kt = 0; kt < 32; ++kt) {
        int k = kt*32 + lh*8;
        bf16x8 a = *(const bf16x8*)&nin_s[lj*1024 + (k ^ ((lj&7)<<3))];
        #pragma unroll
        for (int nt = 0; nt < 4; ++nt) {
            int c = half*256 + w*64 + nt*16 + lj;
            bf16x8 b = *(const bf16x8*)&W1T[(size_t)c*1024 + k];
            acc[nt] = __builtin_amdgcn_mfma_f32_16x16x32_bf16(a, b, acc[nt], 0, 0, 0);
        }
    }
    #pragma unroll
    for (int nt = 0; nt < 4; ++nt) {
        int c = half*256 + w*64 + nt*16 + lj;
        float bv = b1[c];
        #pragma unroll
        for (int r = 0; r < 4; ++r)
            h1g[(size_t)(n0 + lh*4 + r)*512 + c] = f2bf(silu_f(acc[nt][r] + bv));
    }
}

// nf += silu(h1@nW2 + b2) ; 16 rows x 256 cols, 256 blocks
__global__ __launch_bounds__(256) void k_node2(
    float* __restrict__ nf, const unsigned short* __restrict__ h1g,
    const unsigned short* __restrict__ W2T, const float* __restrict__ b2)
{
    __shared__ __align__(16) unsigned short h1_s[16*512];
    int n0 = (blockIdx.x >> 1) * 16, half = blockIdx.x & 1, tid = threadIdx.x;
    for (int idx = tid; idx < 16*64; idx += 256) {
        int m = idx >> 6, k8 = (idx & 63) * 8;
        bf16x8 v = *(const bf16x8*)&h1g[(size_t)(n0+m)*512 + k8];
        *(bf16x8*)&h1_s[m*512 + (k8 ^ ((m&7)<<3))] = v;
    }
    __syncthreads();
    int w = tid >> 6, l = tid & 63, lj = l & 15, lh = l >> 4;
    f32x4 acc[4];
    #pragma unroll
    for (int nt = 0; nt < 4; ++nt) acc[nt] = (f32x4){0.f,0.f,0.f,0.f};
    for (int kt = 0; kt < 16; ++kt) {
        int k = kt*32 + lh*8;
        bf16x8 a = *(const bf16x8*)&h1_s[lj*512 + (k ^ ((lj&7)<<3))];
        #pragma unroll
        for (int nt = 0; nt < 4; ++nt) {
            int c = half*256 + w*64 + nt*16 + lj;
            bf16x8 b = *(const bf16x8*)&W2T[(size_t)c*512 + k];
            acc[nt] = __builtin_amdgcn_mfma_f32_16x16x32_bf16(a, b, acc[nt], 0, 0, 0);
        }
    }
    #pragma unroll
    for (int nt = 0; nt < 4; ++nt) {
        int c = half*256 + w*64 + nt*16 + lj;
        float bv = b2[c];
        #pragma unroll
        for (int r = 0; r < 4; ++r) {
            size_t o = (size_t)(n0 + lh*4 + r)*512 + c;
            nf[o] = nf[o] + silu_f(acc[nt][r] + bv);
        }
    }
}

__global__ __launch_bounds__(256) void k_coord(const float* __restrict__ nf,
                                               const float* __restrict__ cW,
                                               float* __restrict__ out) {
    int gid = blockIdx.x * 256 + threadIdx.x;
    if (gid >= 2048 * 3) return;
    int n = gid / 3, c = gid - n * 3;
    float s = 0.f;
    for (int k = 0; k < 512; ++k) s += nf[n * 512 + k] * cW[k * 3 + c];
    out[576 + gid] = s;
}

__global__ __launch_bounds__(256) void k_graph(const float* __restrict__ nf,
                                               const float* __restrict__ lW,
                                               const float* __restrict__ lat,
                                               float* __restrict__ out) {
    __shared__ float gf[512];
    __shared__ float lo9[9];
    int b = blockIdx.x, tid = threadIdx.x;
    float s0 = 0.f, s1 = 0.f;
    for (int r = 0; r < 32; ++r) {
        s0 += nf[(b * 32 + r) * 512 + tid];
        s1 += nf[(b * 32 + r) * 512 + tid + 256];
    }
    gf[tid]       = s0 * (1.f / 32.f);
    gf[tid + 256] = s1 * (1.f / 32.f);
    __syncthreads();
    if (tid < 9) {
        float s = 0.f;
        for (int k = 0; k < 512; ++k) s += gf[k] * lW[k * 9 + tid];
        lo9[tid] = s;
    }
    __syncthreads();
    if (tid < 9) {
        int i = tid / 3, kk = tid - (tid / 3) * 3;
        float s = lo9[i*3+0] * lat[b*9 + 0*3 + kk]
                + lo9[i*3+1] * lat[b*9 + 1*3 + kk]
                + lo9[i*3+2] * lat[b*9 + 2*3 + kk];
        out[b * 9 + tid] = s;
    }
}

extern "C" void kernel_launch(void* const* d_in, const int* in_sizes, int n_in,
                              void* d_out, int out_size, void* d_ws, size_t ws_size,
                              hipStream_t stream)
{
    const float* t    = (const float*)d_in[0];
    const float* frac = (const float*)d_in[1];
    const float* lat  = (const float*)d_in[2];
    const float* emb  = (const float*)d_in[3];
    const float* Wl   = (const float*)d_in[4];
    const float* bl   = (const float*)d_in[5];
    const float* eW1  = (const float*)d_in[6];
    const float* eb1  = (const float*)d_in[7];
    const float* eW2  = (const float*)d_in[8];
    const float* eb2  = (const float*)d_in[9];
    const float* nW1  = (const float*)d_in[10];
    const float* nb1  = (const float*)d_in[11];
    const float* nW2  = (const float*)d_in[12];
    const float* nb2  = (const float*)d_in[13];
    const float* cW   = (const float*)d_in[14];
    const float* lW   = (const float*)d_in[15];
    const int* atom_types = (const int*)d_in[16];

    float* out  = (float*)d_out;
    float* wsf  = (float*)d_ws;
    float* nf   = wsf + NF_OFF;
    float* Uagg = wsf + UAGG_OFF;   // U' during k_uv/k_edge, then agg (row-exclusive)
    unsigned short* VT  = (unsigned short*)(wsf + VT_OFF);
    unsigned short* h1g = (unsigned short*)(wsf + H1_OFF);
    unsigned short* wbf = (unsigned short*)(wsf + WBF_OFF);

    // allow 128KB dynamic LDS for k_edge (idempotent, capture-safe)
    (void)hipFuncSetAttribute((const void*)k_edge,
                              hipFuncAttributeMaxDynamicSharedMemorySize, 131072);

    k_prep<<<384 + 4*1568, 256, 0, stream>>>(Wl, eW1, eW2, nW1, nW2, wbf);
    k_init<<<256, 256, 0, stream>>>(t, emb, wbf, bl, atom_types, nf);
    for (int l = 0; l < 4; ++l) {
        const unsigned short* uvT  = wbf + SZ_INITT + (size_t)l * SZ_LAYER;
        const unsigned short* w1dT = uvT + SZ_UVT;
        const unsigned short* w2T  = w1dT + SZ_W1DT;
        const unsigned short* nw1T = w2T + SZ_W2T;
        const unsigned short* nw2T = nw1T + SZ_NW1T;
        k_uv<<<256, 256, 0, stream>>>(nf, uvT, lat,
                                      eW1 + (size_t)l*1093*512 + 1024*512,
                                      eb1 + l*512, Uagg, VT);
        k_edge<<<1024, 512, 131072, stream>>>(Uagg, VT, frac, w1dT, w2T,
                                              eb2 + l*512, Uagg);
        k_node1<<<256, 256, 0, stream>>>(nf, Uagg, nw1T, nb1 + l*512, h1g);
        k_node2<<<256, 256, 0, stream>>>(nf, h1g, nw2T, nb2 + l*512);
    }
    k_coord<<<24, 256, 0, stream>>>(nf, cW, out);
    k_graph<<<64, 256, 0, stream>>>(nf, lW, lat, out);
}

// Round 8
// 434.255 us; speedup vs baseline: 5.8957x; 1.5958x over previous
//
#include <hip/hip_runtime.h>
#include <math.h>

// B=64 graphs, A=32 atoms, N=2048 nodes, E=65536 edges, H=512, LAT=256, L=4, DIS=60, EIN=1093
// All weights pre-packed in MFMA-fragment order:
//   tile (kt,nt) of W^T[512 n][K k] stored at ((kt*32 + nt)*64 + lane)*8,
//   lane=(lj=l&15, lh=l>>4) holds W^T[nt*16+lj][kt*32+lh*8 .. +8].
// B-fragment load = one coalesced 16B/lane read (no 16-line scatter).

typedef short bf16x8 __attribute__((ext_vector_type(8)));
typedef float f32x4 __attribute__((ext_vector_type(4)));

__device__ __forceinline__ float silu_f(float x) {
    float e = __builtin_amdgcn_exp2f(x * -1.44269504088896f);
    return x * __builtin_amdgcn_rcpf(1.0f + e);
}
__device__ __forceinline__ unsigned short f2bf(float x) {
    unsigned int u = __float_as_uint(x);
    u += 0x7fffu + ((u >> 16) & 1u);
    return (unsigned short)(u >> 16);
}
__device__ __forceinline__ unsigned int cvt_pk_bf16(float lo, float hi) {
    unsigned int r;
    asm("v_cvt_pk_bf16_f32 %0, %1, %2" : "=v"(r) : "v"(lo), "v"(hi));
    return r;
}

// ---- workspace layout (float offsets) ----
#define NF_OFF    0
#define UAGG_OFF  (2048*512)
#define VT_OFF    (2*2048*512)                 // ushort region 64*16384 = 524288 floats
#define H1_OFF    (VT_OFF + 524288)            // ushort region 2048*512  = 524288 floats
#define WBF_OFF   (H1_OFF + 524288)
// bf16 weight region sizes (ushort elements)
#define SZ_INITT (512*768)
#define SZ_UVT   (1024*512)
#define SZ_W1DT  (512*64)
#define SZ_W2T   (512*512)
#define SZ_NW1T  (512*1024)
#define SZ_NW2T  (512*512)
#define SZ_LAYER (SZ_UVT+SZ_W1DT+SZ_W2T+SZ_NW1T+SZ_NW2T)

// ---- weight transpose+convert+fragment-pack: f32 [K][512] -> packed bf16 ----
__global__ __launch_bounds__(256) void k_prep(
    const float* __restrict__ Wl, const float* __restrict__ eW1,
    const float* __restrict__ eW2, const float* __restrict__ nW1,
    const float* __restrict__ nW2, unsigned short* __restrict__ wbf)
{
    __shared__ float tile[32][33];
    int bid = blockIdx.x;
    const float* src; int K; unsigned short* dst; int t;
    if (bid < 384) { src = Wl; K = 768; dst = wbf; t = bid; }
    else {
        int b = bid - 384; int l = b / 1568; int j = b - l * 1568;
        const float* e1 = eW1 + (size_t)l * 1093 * 512;
        unsigned short* base = wbf + SZ_INITT + (size_t)l * SZ_LAYER;
        if (j < 256)      { src = e1;                       K = 512;  dst = base;                                   t = j; }
        else if (j < 512) { src = e1 + 512*512;             K = 512;  dst = base + 512*512;                         t = j-256; }
        else if (j < 544) { src = e1 + 1033*512;            K = 60;   dst = base + SZ_UVT;                          t = j-512; }
        else if (j < 800) { src = eW2 + (size_t)l*512*512;  K = 512;  dst = base + SZ_UVT+SZ_W1DT;                  t = j-544; }
        else if (j <1312) { src = nW1 + (size_t)l*1024*512; K = 1024; dst = base + SZ_UVT+SZ_W1DT+SZ_W2T;           t = j-800; }
        else              { src = nW2 + (size_t)l*512*512;  K = 512;  dst = base + SZ_UVT+SZ_W1DT+SZ_W2T+SZ_NW1T;   t = j-1312; }
    }
    // region: kt = tr (32 k), n-pair tc (32 n = 2 tiles)
    int tr = t >> 4, tc = t & 15;
    int k0 = tr * 32, nn0 = tc * 32;
    {
        int r8 = threadIdx.x >> 5, cc = threadIdx.x & 31;
        #pragma unroll
        for (int rr = 0; rr < 4; ++rr) {
            int row = rr*8 + r8;
            int k = k0 + row;
            tile[row][cc] = (k < K) ? src[(size_t)k*512 + nn0 + cc] : 0.f;
        }
    }
    __syncthreads();
    // write fragment-packed: thread = (nt_loc, lane, jh)
    int nt_loc = threadIdx.x >> 7;
    int l = (threadIdx.x >> 1) & 63;
    int jh = threadIdx.x & 1;
    int lj = l & 15, lh = l >> 4;
    float v0 = tile[lh*8 + jh*4 + 0][nt_loc*16 + lj];
    float v1 = tile[lh*8 + jh*4 + 1][nt_loc*16 + lj];
    float v2 = tile[lh*8 + jh*4 + 2][nt_loc*16 + lj];
    float v3 = tile[lh*8 + jh*4 + 3][nt_loc*16 + lj];
    uint2 pk = { cvt_pk_bf16(v0, v1), cvt_pk_bf16(v2, v3) };
    *(uint2*)&dst[((size_t)(tr*32 + tc*2 + nt_loc)*64 + l)*8 + jh*4] = pk;
}

// nf0 = concat(emb,t)@Wl + bl : 16 rows x 256 cols per block, 256 blocks
__global__ __launch_bounds__(256) void k_init(
    const float* __restrict__ tvec, const float* __restrict__ emb,
    const unsigned short* __restrict__ WT, const float* __restrict__ bl,
    const int* __restrict__ atom_types, float* __restrict__ nf)
{
    __shared__ __align__(16) unsigned short cat_s[16*768];
    int n0 = (blockIdx.x >> 1) * 16, half = blockIdx.x & 1, tid = threadIdx.x;
    for (int idx = tid; idx < 16*192; idx += 256) {
        int m = idx / 192, q = idx - m * 192;
        int k4 = q * 4, n = n0 + m;
        float4 v;
        if (k4 < 512) v = *(const float4*)&emb[(size_t)(atom_types[n]-1)*512 + k4];
        else          v = *(const float4*)&tvec[(size_t)(n>>5)*256 + (k4-512)];
        uint2 pk = { cvt_pk_bf16(v.x, v.y), cvt_pk_bf16(v.z, v.w) };
        *(uint2*)&cat_s[m*768 + (k4 ^ ((m&7)<<3))] = pk;
    }
    __syncthreads();
    int w = tid >> 6, l = tid & 63, lj = l & 15, lh = l >> 4;
    f32x4 acc[4];
    #pragma unroll
    for (int nt = 0; nt < 4; ++nt) acc[nt] = (f32x4){0.f,0.f,0.f,0.f};
    for (int kt = 0; kt < 24; ++kt) {
        int k = kt*32 + lh*8;
        bf16x8 a = *(const bf16x8*)&cat_s[lj*768 + (k ^ ((lj&7)<<3))];
        #pragma unroll
        for (int nt = 0; nt < 4; ++nt) {
            bf16x8 b = *(const bf16x8*)&WT[(((size_t)kt*32 + half*16 + w*4 + nt)*64 + l)*8];
            acc[nt] = __builtin_amdgcn_mfma_f32_16x16x32_bf16(a, b, acc[nt], 0, 0, 0);
        }
    }
    #pragma unroll
    for (int nt = 0; nt < 4; ++nt) {
        int c = half*256 + w*64 + nt*16 + lj;
        float bv = bl[c];
        #pragma unroll
        for (int r = 0; r < 4; ++r)
            nf[(size_t)(n0 + lh*4 + r)*512 + c] = acc[nt][r] + bv;
    }
}

// half0: U' = nf@W1a + latip@W1c + b1 (f32); half1: VTP (fragment-packed per graph)
__global__ __launch_bounds__(256) void k_uv(
    const float* __restrict__ nf, const unsigned short* __restrict__ WT,
    const float* __restrict__ lat, const float* __restrict__ W1c,
    const float* __restrict__ b1, float* __restrict__ Up,
    unsigned short* __restrict__ VT)
{
    __shared__ __align__(16) unsigned short a_s[16*512];
    int n0 = (blockIdx.x >> 1) * 16, half = blockIdx.x & 1;
    int g = n0 >> 5, j0 = n0 & 31, tid = threadIdx.x;
    for (int idx = tid; idx < 16*128; idx += 256) {
        int m = idx >> 7, q = idx & 127;
        int k4 = q * 4;
        float4 v = *(const float4*)&nf[(size_t)(n0+m)*512 + k4];
        uint2 pk = { cvt_pk_bf16(v.x, v.y), cvt_pk_bf16(v.z, v.w) };
        *(uint2*)&a_s[m*512 + (k4 ^ ((m&7)<<3))] = pk;
    }
    __syncthreads();
    int w = tid >> 6, l = tid & 63, lj = l & 15, lh = l >> 4;
    const unsigned short* Wh = WT + (size_t)half*512*512;
    f32x4 acc[8];
    #pragma unroll
    for (int nt = 0; nt < 8; ++nt) acc[nt] = (f32x4){0.f,0.f,0.f,0.f};
    for (int kt = 0; kt < 16; ++kt) {
        int k = kt*32 + lh*8;
        bf16x8 a = *(const bf16x8*)&a_s[lj*512 + (k ^ ((lj&7)<<3))];
        #pragma unroll
        for (int nt = 0; nt < 8; ++nt) {
            bf16x8 b = *(const bf16x8*)&Wh[(((size_t)kt*32 + w*8 + nt)*64 + l)*8];
            acc[nt] = __builtin_amdgcn_mfma_f32_16x16x32_bf16(a, b, acc[nt], 0, 0, 0);
        }
    }
    if (half == 0) {
        float L[9], lip[9];
        #pragma unroll
        for (int i = 0; i < 9; ++i) L[i] = lat[g*9 + i];
        #pragma unroll
        for (int i = 0; i < 3; ++i)
            #pragma unroll
            for (int kk = 0; kk < 3; ++kk)
                lip[i*3+kk] = L[i*3]*L[kk*3] + L[i*3+1]*L[kk*3+1] + L[i*3+2]*L[kk*3+2];
        #pragma unroll
        for (int nt = 0; nt < 8; ++nt) {
            int c = w*128 + nt*16 + lj;
            float p3 = b1[c];
            #pragma unroll
            for (int t9 = 0; t9 < 9; ++t9) p3 += lip[t9] * W1c[t9*512 + c];
            #pragma unroll
            for (int r = 0; r < 4; ++r)
                Up[(size_t)(n0 + lh*4 + r)*512 + c] = acc[nt][r] + p3;
        }
    } else {
        // VTP[g]: tile ct = c/16; lane l2=(lj, j/8); slot j%8; j = j0 + lh*4 + r
        int l2 = lj + 16*((j0 + lh*4) >> 3);
        int off8 = (lh*4) & 7;
        #pragma unroll
        for (int nt = 0; nt < 8; ++nt) {
            int ct = w*8 + nt;
            uint2 pk = { cvt_pk_bf16(acc[nt][0], acc[nt][1]),
                         cvt_pk_bf16(acc[nt][2], acc[nt][3]) };
            *(uint2*)&VT[(size_t)g*16384 + (size_t)ct*512 + l2*8 + off8] = pk;
        }
    }
}

// fused edge pipeline: 2 src nodes per block (M=64), 512 threads (8 waves), grid 1024.
// Wave wid owns cols [wid*64,+64). stage1 swapped-MFMA -> ef1 (64KB LDS);
// stage2 barrier-free K-loop with fragment-packed coalesced W2 loads.
__global__ __launch_bounds__(512) void k_edge(
    const float* __restrict__ Up, const unsigned short* __restrict__ VT,
    const float* __restrict__ frac,
    const unsigned short* __restrict__ W1dT,
    const unsigned short* __restrict__ W2T, const float* __restrict__ b2,
    float* __restrict__ agg)
{
    __shared__ __align__(16) unsigned short ef1_s[64*512];
    int n0 = blockIdx.x * 2, g = n0 >> 5, tid = threadIdx.x;
    int wid = tid >> 6, l = tid & 63, lj = l & 15, lh = l >> 4;
    const unsigned short* VTg = VT + (size_t)g*16384;

    // ---------------- stage 1 ----------------
    {
        float di[2][2][3];
        #pragma unroll
        for (int h = 0; h < 2; ++h)
            #pragma unroll
            for (int dd = 0; dd < 2; ++dd) {
                int dstn = g*32 + dd*16 + lj;
                #pragma unroll
                for (int comp = 0; comp < 3; ++comp) {
                    float d = frac[dstn*3 + comp] - frac[(n0+h)*3 + comp];
                    d -= floorf(d);
                    di[h][dd][comp] = d;
                }
            }
        bf16x8 fdf[2][4];
        #pragma unroll
        for (int kt = 0; kt < 2; ++kt)
            #pragma unroll
            for (int mt = 0; mt < 4; ++mt) {
                int h = mt >> 1, dd = mt & 1;
                #pragma unroll
                for (int kk = 0; kk < 8; ++kk) {
                    int k = kt*32 + lh*8 + kk;
                    float val = 0.f;
                    if (k < 60) {
                        int isCos = k >= 30;
                        int dq = k - (isCos ? 30 : 0);
                        int comp = dq >= 20 ? 2 : (dq >= 10 ? 1 : 0);
                        int f = dq - comp*10;
                        float u = di[h][dd][comp] * (float)f;
                        u -= floorf(u);
                        val = isCos ? __builtin_amdgcn_cosf(u) : __builtin_amdgcn_sinf(u);
                    }
                    fdf[kt][mt][kk] = (short)f2bf(val);
                }
            }
        bf16x8 ind[2];
        #pragma unroll
        for (int dd = 0; dd < 2; ++dd)
            #pragma unroll
            for (int kk = 0; kk < 8; ++kk)
                ind[dd][kk] = (short)((lh*8 + kk == dd*16 + lj) ? 0x3F80 : 0);

        #pragma unroll
        for (int q = 0; q < 4; ++q) {
            int ct = wid*4 + q;
            f32x4 a1[4];
            #pragma unroll
            for (int mt = 0; mt < 4; ++mt) a1[mt] = (f32x4){0.f,0.f,0.f,0.f};
            bf16x8 vf = *(const bf16x8*)&VTg[((size_t)ct*64 + l)*8];
            #pragma unroll
            for (int mt = 0; mt < 4; ++mt)
                a1[mt] = __builtin_amdgcn_mfma_f32_16x16x32_bf16(vf, ind[mt&1], a1[mt], 0, 0, 0);
            #pragma unroll
            for (int kt = 0; kt < 2; ++kt) {
                bf16x8 wf = *(const bf16x8*)&W1dT[(((size_t)kt*32 + ct)*64 + l)*8];
                #pragma unroll
                for (int mt = 0; mt < 4; ++mt)
                    a1[mt] = __builtin_amdgcn_mfma_f32_16x16x32_bf16(wf, fdf[kt][mt], a1[mt], 0, 0, 0);
            }
            // epilogue: + U', silu, bf16 -> ef1_s (ef1^T -> ef1 rows)
            int c0 = wid*64 + q*16 + lh*4;
            float4 bs0 = *(const float4*)&Up[(size_t)n0*512 + c0];
            float4 bs1 = *(const float4*)&Up[(size_t)(n0+1)*512 + c0];
            #pragma unroll
            for (int mt = 0; mt < 4; ++mt) {
                float4 bb = (mt >> 1) ? bs1 : bs0;
                int m = mt*16 + lj;
                float x0 = silu_f(a1[mt][0] + bb.x);
                float x1 = silu_f(a1[mt][1] + bb.y);
                float x2 = silu_f(a1[mt][2] + bb.z);
                float x3 = silu_f(a1[mt][3] + bb.w);
                uint2 pk = { cvt_pk_bf16(x0, x1), cvt_pk_bf16(x2, x3) };
                *(uint2*)&ef1_s[m*512 + (c0 ^ ((m&7)<<3))] = pk;
            }
        }
    }
    __syncthreads();

    // ---------------- stage 2 (barrier-free) ----------------
    f32x4 acc2[4][4];
    #pragma unroll
    for (int mt = 0; mt < 4; ++mt)
        #pragma unroll
        for (int nt = 0; nt < 4; ++nt) acc2[mt][nt] = (f32x4){0.f,0.f,0.f,0.f};

    for (int kt = 0; kt < 16; ++kt) {
        int k = kt*32 + lh*8;
        bf16x8 af[4];
        #pragma unroll
        for (int mt = 0; mt < 4; ++mt) {
            int m = mt*16 + lj;
            af[mt] = *(const bf16x8*)&ef1_s[m*512 + (k ^ ((m&7)<<3))];
        }
        #pragma unroll
        for (int nt = 0; nt < 4; ++nt) {
            bf16x8 bfr = *(const bf16x8*)&W2T[(((size_t)kt*32 + wid*4 + nt)*64 + l)*8];
            #pragma unroll
            for (int mt = 0; mt < 4; ++mt)
                acc2[mt][nt] = __builtin_amdgcn_mfma_f32_16x16x32_bf16(af[mt], bfr, acc2[mt][nt], 0, 0, 0);
        }
    }

    // epilogue: silu + per-node column mean
    #pragma unroll
    for (int nt = 0; nt < 4; ++nt) {
        int cc = wid*64 + nt*16 + lj;
        float bv = b2[cc];
        float s0 = 0.f, s1 = 0.f;
        #pragma unroll
        for (int mt = 0; mt < 4; ++mt)
            #pragma unroll
            for (int r = 0; r < 4; ++r) {
                float x = silu_f(acc2[mt][nt][r] + bv);
                if (mt < 2) s0 += x; else s1 += x;
            }
        s0 += __shfl_xor(s0, 16); s0 += __shfl_xor(s0, 32);
        s1 += __shfl_xor(s1, 16); s1 += __shfl_xor(s1, 32);
        if (lh == 0) {
            agg[(size_t)n0*512 + cc]     = s0 * (1.0f/32.0f);
            agg[(size_t)(n0+1)*512 + cc] = s1 * (1.0f/32.0f);
        }
    }
}

// h1 = silu([nf,agg]@nW1 + b1) -> bf16 global ; 16 rows x 256 cols, 256 blocks
__global__ __launch_bounds__(256) void k_node1(
    const float* __restrict__ nf, const float* __restrict__ agg,
    const unsigned short* __restrict__ W1T, const float* __restrict__ b1,
    unsigned short* __restrict__ h1g)
{
    __shared__ __align__(16) unsigned short nin_s[16*1024];
    int n0 = (blockIdx.x >> 1) * 16, half = blockIdx.x & 1, tid = threadIdx.x;
    for (int idx = tid; idx < 16*256; idx += 256) {
        int m = idx >> 8, q = idx & 255;
        int k4 = q * 4;
        float4 v = (k4 < 512) ? *(const float4*)&nf[(size_t)(n0+m)*512 + k4]
                              : *(const float4*)&agg[(size_t)(n0+m)*512 + (k4-512)];
        uint2 pk = { cvt_pk_bf16(v.x, v.y), cvt_pk_bf16(v.z, v.w) };
        *(uint2*)&nin_s[m*1024 + (k4 ^ ((m&7)<<3))] = pk;
    }
    __syncthreads();
    int w = tid >> 6, l = tid & 63, lj = l & 15, lh = l >> 4;
    f32x4 acc[4];
    #pragma unroll
    for (int nt = 0; nt < 4; ++nt) acc[nt] = (f32x4){0.f,0.f,0.f,0.f};
    for (int kt = 0; kt < 32; ++kt) {
        int k = kt*32 + lh*8;
        bf16x8 a = *(const bf16x8*)&nin_s[lj*1024 + (k ^ ((lj&7)<<3))];
        #pragma unroll
        for (int nt = 0; nt < 4; ++nt) {
            bf16x8 b = *(const bf16x8*)&W1T[(((size_t)kt*32 + half*16 + w*4 + nt)*64 + l)*8];
            acc[nt] = __builtin_amdgcn_mfma_f32_16x16x32_bf16(a, b, acc[nt], 0, 0, 0);
        }
    }
    #pragma unroll
    for (int nt = 0; nt < 4; ++nt) {
        int c = half*256 + w*64 + nt*16 + lj;
        float bv = b1[c];
        #pragma unroll
        for (int r = 0; r < 4; ++r)
            h1g[(size_t)(n0 + lh*4 + r)*512 + c] = f2bf(silu_f(acc[nt][r] + bv));
    }
}

// nf += silu(h1@nW2 + b2) ; 16 rows x 256 cols, 256 blocks
__global__ __launch_bounds__(256) void k_node2(
    float* __restrict__ nf, const unsigned short* __restrict__ h1g,
    const unsigned short* __restrict__ W2T, const float* __restrict__ b2)
{
    __shared__ __align__(16) unsigned short h1_s[16*512];
    int n0 = (blockIdx.x >> 1) * 16, half = blockIdx.x & 1, tid = threadIdx.x;
    for (int idx = tid; idx < 16*64; idx += 256) {
        int m = idx >> 6, k8 = (idx & 63) * 8;
        bf16x8 v = *(const bf16x8*)&h1g[(size_t)(n0+m)*512 + k8];
        *(bf16x8*)&h1_s[m*512 + (k8 ^ ((m&7)<<3))] = v;
    }
    __syncthreads();
    int w = tid >> 6, l = tid & 63, lj = l & 15, lh = l >> 4;
    f32x4 acc[4];
    #pragma unroll
    for (int nt = 0; nt < 4; ++nt) acc[nt] = (f32x4){0.f,0.f,0.f,0.f};
    for (int kt = 0; kt < 16; ++kt) {
        int k = kt*32 + lh*8;
        bf16x8 a = *(const bf16x8*)&h1_s[lj*512 + (k ^ ((lj&7)<<3))];
        #pragma unroll
        for (int nt = 0; nt < 4; ++nt) {
            bf16x8 b = *(const bf16x8*)&W2T[(((size_t)kt*32 + half*16 + w*4 + nt)*64 + l)*8];
            acc[nt] = __builtin_amdgcn_mfma_f32_16x16x32_bf16(a, b, acc[nt], 0, 0, 0);
        }
    }
    #pragma unroll
    for (int nt = 0; nt < 4; ++nt) {
        int c = half*256 + w*64 + nt*16 + lj;
        float bv = b2[c];
        #pragma unroll
        for (int r = 0; r < 4; ++r) {
            size_t o = (size_t)(n0 + lh*4 + r)*512 + c;
            nf[o] = nf[o] + silu_f(acc[nt][r] + bv);
        }
    }
}

__global__ __launch_bounds__(256) void k_coord(const float* __restrict__ nf,
                                               const float* __restrict__ cW,
                                               float* __restrict__ out) {
    int gid = blockIdx.x * 256 + threadIdx.x;
    if (gid >= 2048 * 3) return;
    int n = gid / 3, c = gid - n * 3;
    float s = 0.f;
    for (int k = 0; k < 512; ++k) s += nf[n * 512 + k] * cW[k * 3 + c];
    out[576 + gid] = s;
}

__global__ __launch_bounds__(256) void k_graph(const float* __restrict__ nf,
                                               const float* __restrict__ lW,
                                               const float* __restrict__ lat,
                                               float* __restrict__ out) {
    __shared__ float gf[512];
    __shared__ float lo9[9];
    int b = blockIdx.x, tid = threadIdx.x;
    float s0 = 0.f, s1 = 0.f;
    for (int r = 0; r < 32; ++r) {
        s0 += nf[(b * 32 + r) * 512 + tid];
        s1 += nf[(b * 32 + r) * 512 + tid + 256];
    }
    gf[tid]       = s0 * (1.f / 32.f);
    gf[tid + 256] = s1 * (1.f / 32.f);
    __syncthreads();
    if (tid < 9) {
        float s = 0.f;
        for (int k = 0; k < 512; ++k) s += gf[k] * lW[k * 9 + tid];
        lo9[tid] = s;
    }
    __syncthreads();
    if (tid < 9) {
        int i = tid / 3, kk = tid - (tid / 3) * 3;
        float s = lo9[i*3+0] * lat[b*9 + 0*3 + kk]
                + lo9[i*3+1] * lat[b*9 + 1*3 + kk]
                + lo9[i*3+2] * lat[b*9 + 2*3 + kk];
        out[b * 9 + tid] = s;
    }
}

extern "C" void kernel_launch(void* const* d_in, const int* in_sizes, int n_in,
                              void* d_out, int out_size, void* d_ws, size_t ws_size,
                              hipStream_t stream)
{
    const float* t    = (const float*)d_in[0];
    const float* frac = (const float*)d_in[1];
    const float* lat  = (const float*)d_in[2];
    const float* emb  = (const float*)d_in[3];
    const float* Wl   = (const float*)d_in[4];
    const float* bl   = (const float*)d_in[5];
    const float* eW1  = (const float*)d_in[6];
    const float* eb1  = (const float*)d_in[7];
    const float* eW2  = (const float*)d_in[8];
    const float* eb2  = (const float*)d_in[9];
    const float* nW1  = (const float*)d_in[10];
    const float* nb1  = (const float*)d_in[11];
    const float* nW2  = (const float*)d_in[12];
    const float* nb2  = (const float*)d_in[13];
    const float* cW   = (const float*)d_in[14];
    const float* lW   = (const float*)d_in[15];
    const int* atom_types = (const int*)d_in[16];

    float* out  = (float*)d_out;
    float* wsf  = (float*)d_ws;
    float* nf   = wsf + NF_OFF;
    float* Uagg = wsf + UAGG_OFF;   // U' during k_uv/k_edge, then agg (row-exclusive)
    unsigned short* VT  = (unsigned short*)(wsf + VT_OFF);
    unsigned short* h1g = (unsigned short*)(wsf + H1_OFF);
    unsigned short* wbf = (unsigned short*)(wsf + WBF_OFF);

    k_prep<<<384 + 4*1568, 256, 0, stream>>>(Wl, eW1, eW2, nW1, nW2, wbf);
    k_init<<<256, 256, 0, stream>>>(t, emb, wbf, bl, atom_types, nf);
    for (int l = 0; l < 4; ++l) {
        const unsigned short* uvT  = wbf + SZ_INITT + (size_t)l * SZ_LAYER;
        const unsigned short* w1dT = uvT + SZ_UVT;
        const unsigned short* w2T  = w1dT + SZ_W1DT;
        const unsigned short* nw1T = w2T + SZ_W2T;
        const unsigned short* nw2T = nw1T + SZ_NW1T;
        k_uv<<<256, 256, 0, stream>>>(nf, uvT, lat,
                                      eW1 + (size_t)l*1093*512 + 1024*512,
                                      eb1 + l*512, Uagg, VT);
        k_edge<<<1024, 512, 0, stream>>>(Uagg, VT, frac, w1dT, w2T,
                                         eb2 + l*512, Uagg);
        k_node1<<<256, 256, 0, stream>>>(nf, Uagg, nw1T, nb1 + l*512, h1g);
        k_node2<<<256, 256, 0, stream>>>(nf, h1g, nw2T, nb2 + l*512);
    }
    k_coord<<<24, 256, 0, stream>>>(nf, cW, out);
    k_graph<<<64, 256, 0, stream>>>(nf, lW, lat, out);
}

// Round 9
// 385.699 us; speedup vs baseline: 6.6380x; 1.1259x over previous
//
#include <hip/hip_runtime.h>
#include <math.h>

// B=64 graphs, A=32 atoms, N=2048 nodes, E=65536 edges, H=512, LAT=256, L=4, DIS=60, EIN=1093
// Weights pre-packed in MFMA-fragment order: tile (kt,nt) of W^T[512][K] at
// ((kt*32+nt)*64+lane)*8 ; lane (lj=l&15, lh=l>>4) holds W^T[nt*16+lj][kt*32+lh*8..+8].
// fd sinusoid fragments precomputed once (layer-invariant). V emitted in f32 D-layout.

typedef short bf16x8 __attribute__((ext_vector_type(8)));
typedef float f32x4 __attribute__((ext_vector_type(4)));

__device__ __forceinline__ float silu_f(float x) {
    float e = __builtin_amdgcn_exp2f(x * -1.44269504088896f);
    return x * __builtin_amdgcn_rcpf(1.0f + e);
}
__device__ __forceinline__ unsigned short f2bf(float x) {
    unsigned int u = __float_as_uint(x);
    u += 0x7fffu + ((u >> 16) & 1u);
    return (unsigned short)(u >> 16);
}
__device__ __forceinline__ unsigned int cvt_pk_bf16(float lo, float hi) {
    unsigned int r;
    asm("v_cvt_pk_bf16_f32 %0, %1, %2" : "=v"(r) : "v"(lo), "v"(hi));
    return r;
}

// ---- workspace layout (float offsets) ----
#define NF_OFF    0
#define UAGG_OFF  (2048*512)
#define VTD_OFF   (2*2048*512)                   // f32 region 64*16384 = 1048576 floats
#define H1_OFF    (VTD_OFF + 64*16384)           // ushort region 2048*512 = 524288 floats
#define WBF_OFF   (H1_OFF + 524288)
// bf16 weight region sizes (ushort elements)
#define SZ_INITT (512*768)
#define SZ_UVT   (1024*512)
#define SZ_W1DT  (512*64)
#define SZ_W2T   (512*512)
#define SZ_NW1T  (512*1024)
#define SZ_NW2T  (512*512)
#define SZ_LAYER (SZ_UVT+SZ_W1DT+SZ_W2T+SZ_NW1T+SZ_NW2T)
#define WBF_FLOATS ((SZ_INITT + 4*SZ_LAYER + 1)/2)
#define FDP_OFF   (WBF_OFF + WBF_FLOATS)         // ushort region 1024*8*512 = 4194304 ushorts

// ---- weight transpose+convert+fragment-pack: f32 [K][512] -> packed bf16 ----
__global__ __launch_bounds__(256) void k_prep(
    const float* __restrict__ Wl, const float* __restrict__ eW1,
    const float* __restrict__ eW2, const float* __restrict__ nW1,
    const float* __restrict__ nW2, unsigned short* __restrict__ wbf)
{
    __shared__ float tile[32][33];
    int bid = blockIdx.x;
    const float* src; int K; unsigned short* dst; int t;
    if (bid < 384) { src = Wl; K = 768; dst = wbf; t = bid; }
    else {
        int b = bid - 384; int l = b / 1568; int j = b - l * 1568;
        const float* e1 = eW1 + (size_t)l * 1093 * 512;
        unsigned short* base = wbf + SZ_INITT + (size_t)l * SZ_LAYER;
        if (j < 256)      { src = e1;                       K = 512;  dst = base;                                   t = j; }
        else if (j < 512) { src = e1 + 512*512;             K = 512;  dst = base + 512*512;                         t = j-256; }
        else if (j < 544) { src = e1 + 1033*512;            K = 60;   dst = base + SZ_UVT;                          t = j-512; }
        else if (j < 800) { src = eW2 + (size_t)l*512*512;  K = 512;  dst = base + SZ_UVT+SZ_W1DT;                  t = j-544; }
        else if (j <1312) { src = nW1 + (size_t)l*1024*512; K = 1024; dst = base + SZ_UVT+SZ_W1DT+SZ_W2T;           t = j-800; }
        else              { src = nW2 + (size_t)l*512*512;  K = 512;  dst = base + SZ_UVT+SZ_W1DT+SZ_W2T+SZ_NW1T;   t = j-1312; }
    }
    int tr = t >> 4, tc = t & 15;
    int k0 = tr * 32, nn0 = tc * 32;
    {
        int r8 = threadIdx.x >> 5, cc = threadIdx.x & 31;
        #pragma unroll
        for (int rr = 0; rr < 4; ++rr) {
            int row = rr*8 + r8;
            int k = k0 + row;
            tile[row][cc] = (k < K) ? src[(size_t)k*512 + nn0 + cc] : 0.f;
        }
    }
    __syncthreads();
    int nt_loc = threadIdx.x >> 7;
    int l = (threadIdx.x >> 1) & 63;
    int jh = threadIdx.x & 1;
    int lj = l & 15, lh = l >> 4;
    float v0 = tile[lh*8 + jh*4 + 0][nt_loc*16 + lj];
    float v1 = tile[lh*8 + jh*4 + 1][nt_loc*16 + lj];
    float v2 = tile[lh*8 + jh*4 + 2][nt_loc*16 + lj];
    float v3 = tile[lh*8 + jh*4 + 3][nt_loc*16 + lj];
    uint2 pk = { cvt_pk_bf16(v0, v1), cvt_pk_bf16(v2, v3) };
    *(uint2*)&dst[((size_t)(tr*32 + tc*2 + nt_loc)*64 + l)*8 + jh*4] = pk;
}

// fd sinusoid B-fragments, once for all layers: fdP[block][kt*4+mt][lane][8]
__global__ __launch_bounds__(64) void k_fd(const float* __restrict__ frac,
                                           unsigned short* __restrict__ fdP)
{
    int bid = blockIdx.x;                  // 1024 blocks = 2 src nodes each
    int n0 = bid * 2, g = n0 >> 5;
    int l = threadIdx.x, lj = l & 15, lh = l >> 4;
    float di[2][2][3];
    #pragma unroll
    for (int h = 0; h < 2; ++h)
        #pragma unroll
        for (int dd = 0; dd < 2; ++dd) {
            int dstn = g*32 + dd*16 + lj;
            #pragma unroll
            for (int comp = 0; comp < 3; ++comp) {
                float d = frac[dstn*3 + comp] - frac[(n0+h)*3 + comp];
                d -= floorf(d);
                di[h][dd][comp] = d;
            }
        }
    #pragma unroll
    for (int kt = 0; kt < 2; ++kt)
        #pragma unroll
        for (int mt = 0; mt < 4; ++mt) {
            int h = mt >> 1, dd = mt & 1;
            unsigned int w[4];
            #pragma unroll
            for (int p = 0; p < 4; ++p) {
                float vv[2];
                #pragma unroll
                for (int e = 0; e < 2; ++e) {
                    int k = kt*32 + lh*8 + p*2 + e;
                    float val = 0.f;
                    if (k < 60) {
                        int isCos = k >= 30;
                        int dq = k - (isCos ? 30 : 0);
                        int comp = dq >= 20 ? 2 : (dq >= 10 ? 1 : 0);
                        int f = dq - comp*10;
                        float u = di[h][dd][comp] * (float)f;
                        u -= floorf(u);
                        val = isCos ? __builtin_amdgcn_cosf(u) : __builtin_amdgcn_sinf(u);
                    }
                    vv[e] = val;
                }
                w[p] = cvt_pk_bf16(vv[0], vv[1]);
            }
            uint4 pk = { w[0], w[1], w[2], w[3] };
            *(uint4*)&fdP[(((size_t)bid*8 + kt*4 + mt)*64 + l)*8] = pk;
        }
}

// nf0 = concat(emb,t)@Wl + bl : 16 rows x 256 cols per block, 256 blocks
__global__ __launch_bounds__(256) void k_init(
    const float* __restrict__ tvec, const float* __restrict__ emb,
    const unsigned short* __restrict__ WT, const float* __restrict__ bl,
    const int* __restrict__ atom_types, float* __restrict__ nf)
{
    __shared__ __align__(16) unsigned short cat_s[16*768];
    int n0 = (blockIdx.x >> 1) * 16, half = blockIdx.x & 1, tid = threadIdx.x;
    for (int idx = tid; idx < 16*192; idx += 256) {
        int m = idx / 192, q = idx - m * 192;
        int k4 = q * 4, n = n0 + m;
        float4 v;
        if (k4 < 512) v = *(const float4*)&emb[(size_t)(atom_types[n]-1)*512 + k4];
        else          v = *(const float4*)&tvec[(size_t)(n>>5)*256 + (k4-512)];
        uint2 pk = { cvt_pk_bf16(v.x, v.y), cvt_pk_bf16(v.z, v.w) };
        *(uint2*)&cat_s[m*768 + (k4 ^ ((m&7)<<3))] = pk;
    }
    __syncthreads();
    int w = tid >> 6, l = tid & 63, lj = l & 15, lh = l >> 4;
    f32x4 acc[4];
    #pragma unroll
    for (int nt = 0; nt < 4; ++nt) acc[nt] = (f32x4){0.f,0.f,0.f,0.f};
    for (int kt = 0; kt < 24; ++kt) {
        int k = kt*32 + lh*8;
        bf16x8 a = *(const bf16x8*)&cat_s[lj*768 + (k ^ ((lj&7)<<3))];
        #pragma unroll
        for (int nt = 0; nt < 4; ++nt) {
            bf16x8 b = *(const bf16x8*)&WT[(((size_t)kt*32 + half*16 + w*4 + nt)*64 + l)*8];
            acc[nt] = __builtin_amdgcn_mfma_f32_16x16x32_bf16(a, b, acc[nt], 0, 0, 0);
        }
    }
    #pragma unroll
    for (int nt = 0; nt < 4; ++nt) {
        int c = half*256 + w*64 + nt*16 + lj;
        float bv = bl[c];
        #pragma unroll
        for (int r = 0; r < 4; ++r)
            nf[(size_t)(n0 + lh*4 + r)*512 + c] = acc[nt][r] + bv;
    }
}

// half0: U' = nf@W1a + latip@W1c + b1 (f32); half1: VTD f32 D-layout per graph
__global__ __launch_bounds__(256) void k_uv(
    const float* __restrict__ nf, const unsigned short* __restrict__ WT,
    const float* __restrict__ lat, const float* __restrict__ W1c,
    const float* __restrict__ b1, float* __restrict__ Up,
    float* __restrict__ VTD)
{
    __shared__ __align__(16) unsigned short a_s[16*512];
    int n0 = (blockIdx.x >> 1) * 16, half = blockIdx.x & 1;
    int g = n0 >> 5, tid = threadIdx.x;
    for (int idx = tid; idx < 16*128; idx += 256) {
        int m = idx >> 7, q = idx & 127;
        int k4 = q * 4;
        float4 v = *(const float4*)&nf[(size_t)(n0+m)*512 + k4];
        uint2 pk = { cvt_pk_bf16(v.x, v.y), cvt_pk_bf16(v.z, v.w) };
        *(uint2*)&a_s[m*512 + (k4 ^ ((m&7)<<3))] = pk;
    }
    __syncthreads();
    int w = tid >> 6, l = tid & 63, lj = l & 15, lh = l >> 4;
    const unsigned short* Wh = WT + (size_t)half*512*512;
    f32x4 acc[8];
    #pragma unroll
    for (int nt = 0; nt < 8; ++nt) acc[nt] = (f32x4){0.f,0.f,0.f,0.f};
    for (int kt = 0; kt < 16; ++kt) {
        int k = kt*32 + lh*8;
        bf16x8 a = *(const bf16x8*)&a_s[lj*512 + (k ^ ((lj&7)<<3))];
        #pragma unroll
        for (int nt = 0; nt < 8; ++nt) {
            bf16x8 b = *(const bf16x8*)&Wh[(((size_t)kt*32 + w*8 + nt)*64 + l)*8];
            acc[nt] = __builtin_amdgcn_mfma_f32_16x16x32_bf16(a, b, acc[nt], 0, 0, 0);
        }
    }
    if (half == 0) {
        float L[9], lip[9];
        #pragma unroll
        for (int i = 0; i < 9; ++i) L[i] = lat[g*9 + i];
        #pragma unroll
        for (int i = 0; i < 3; ++i)
            #pragma unroll
            for (int kk = 0; kk < 3; ++kk)
                lip[i*3+kk] = L[i*3]*L[kk*3] + L[i*3+1]*L[kk*3+1] + L[i*3+2]*L[kk*3+2];
        #pragma unroll
        for (int nt = 0; nt < 8; ++nt) {
            int c = w*128 + nt*16 + lj;
            float p3 = b1[c];
            #pragma unroll
            for (int t9 = 0; t9 < 9; ++t9) p3 += lip[t9] * W1c[t9*512 + c];
            #pragma unroll
            for (int r = 0; r < 4; ++r)
                Up[(size_t)(n0 + lh*4 + r)*512 + c] = acc[nt][r] + p3;
        }
    } else {
        // VTD[g][ct][dd][lrow=lh*4+rr][lcol=lj] = V[g*32+dd*16+lrow][ct*16+lcol]
        int dd = (n0 & 31) >> 4;
        #pragma unroll
        for (int nt = 0; nt < 8; ++nt) {
            int ct = w*8 + nt;
            #pragma unroll
            for (int rr = 0; rr < 4; ++rr)
                VTD[(size_t)g*16384 + ct*512 + dd*256 + (lh*4+rr)*16 + lj] = acc[nt][rr];
        }
    }
}

// fused edge pipeline: 2 src nodes/block (M=64), 512 threads (8 waves), grid 1024.
// stage1: a1 init = VTD float4 (V[dst] pre-placed in D-layout), += W1dT x fdP (MFMA),
//         + U', silu -> ef1_s (64KB LDS). stage2: barrier-free K-loop, packed W2 frags.
__global__ __launch_bounds__(512) void k_edge(
    const float* __restrict__ Up, const float* __restrict__ VTD,
    const unsigned short* __restrict__ fdP,
    const unsigned short* __restrict__ W1dT,
    const unsigned short* __restrict__ W2T, const float* __restrict__ b2,
    float* __restrict__ agg)
{
    __shared__ __align__(16) unsigned short ef1_s[64*512];
    int n0 = blockIdx.x * 2, g = n0 >> 5, tid = threadIdx.x;
    int wid = tid >> 6, l = tid & 63, lj = l & 15, lh = l >> 4;

    // ---------------- stage 1 ----------------
    {
        bf16x8 fdf[2][4];
        #pragma unroll
        for (int kt = 0; kt < 2; ++kt)
            #pragma unroll
            for (int mt = 0; mt < 4; ++mt)
                fdf[kt][mt] = *(const bf16x8*)&fdP[(((size_t)blockIdx.x*8 + kt*4 + mt)*64 + l)*8];

        #pragma unroll
        for (int q = 0; q < 4; ++q) {
            int ct = wid*4 + q;
            f32x4 a1[4];
            #pragma unroll
            for (int mt = 0; mt < 4; ++mt)
                a1[mt] = *(const f32x4*)&VTD[(size_t)g*16384 + ct*512 + (mt&1)*256 + lj*16 + lh*4];
            #pragma unroll
            for (int kt = 0; kt < 2; ++kt) {
                bf16x8 wf = *(const bf16x8*)&W1dT[(((size_t)kt*32 + ct)*64 + l)*8];
                #pragma unroll
                for (int mt = 0; mt < 4; ++mt)
                    a1[mt] = __builtin_amdgcn_mfma_f32_16x16x32_bf16(wf, fdf[kt][mt], a1[mt], 0, 0, 0);
            }
            // epilogue: + U', silu, bf16 -> ef1_s (ef1^T -> ef1 rows)
            int c0 = wid*64 + q*16 + lh*4;
            float4 bs0 = *(const float4*)&Up[(size_t)n0*512 + c0];
            float4 bs1 = *(const float4*)&Up[(size_t)(n0+1)*512 + c0];
            #pragma unroll
            for (int mt = 0; mt < 4; ++mt) {
                float4 bb = (mt >> 1) ? bs1 : bs0;
                int m = mt*16 + lj;
                float x0 = silu_f(a1[mt][0] + bb.x);
                float x1 = silu_f(a1[mt][1] + bb.y);
                float x2 = silu_f(a1[mt][2] + bb.z);
                float x3 = silu_f(a1[mt][3] + bb.w);
                uint2 pk = { cvt_pk_bf16(x0, x1), cvt_pk_bf16(x2, x3) };
                *(uint2*)&ef1_s[m*512 + (c0 ^ ((m&7)<<3))] = pk;
            }
        }
    }
    __syncthreads();

    // ---------------- stage 2 (barrier-free) ----------------
    f32x4 acc2[4][4];
    #pragma unroll
    for (int mt = 0; mt < 4; ++mt)
        #pragma unroll
        for (int nt = 0; nt < 4; ++nt) acc2[mt][nt] = (f32x4){0.f,0.f,0.f,0.f};

    for (int kt = 0; kt < 16; ++kt) {
        int k = kt*32 + lh*8;
        bf16x8 af[4];
        #pragma unroll
        for (int mt = 0; mt < 4; ++mt) {
            int m = mt*16 + lj;
            af[mt] = *(const bf16x8*)&ef1_s[m*512 + (k ^ ((m&7)<<3))];
        }
        #pragma unroll
        for (int nt = 0; nt < 4; ++nt) {
            bf16x8 bfr = *(const bf16x8*)&W2T[(((size_t)kt*32 + wid*4 + nt)*64 + l)*8];
            #pragma unroll
            for (int mt = 0; mt < 4; ++mt)
                acc2[mt][nt] = __builtin_amdgcn_mfma_f32_16x16x32_bf16(af[mt], bfr, acc2[mt][nt], 0, 0, 0);
        }
    }

    // epilogue: silu + per-node column mean
    #pragma unroll
    for (int nt = 0; nt < 4; ++nt) {
        int cc = wid*64 + nt*16 + lj;
        float bv = b2[cc];
        float s0 = 0.f, s1 = 0.f;
        #pragma unroll
        for (int mt = 0; mt < 4; ++mt)
            #pragma unroll
            for (int r = 0; r < 4; ++r) {
                float x = silu_f(acc2[mt][nt][r] + bv);
                if (mt < 2) s0 += x; else s1 += x;
            }
        s0 += __shfl_xor(s0, 16); s0 += __shfl_xor(s0, 32);
        s1 += __shfl_xor(s1, 16); s1 += __shfl_xor(s1, 32);
        if (lh == 0) {
            agg[(size_t)n0*512 + cc]     = s0 * (1.0f/32.0f);
            agg[(size_t)(n0+1)*512 + cc] = s1 * (1.0f/32.0f);
        }
    }
}

// h1 = silu([nf,agg]@nW1 + b1) -> bf16 global ; 16 rows x 256 cols, 256 blocks
__global__ __launch_bounds__(256) void k_node1(
    const float* __restrict__ nf, const float* __restrict__ agg,
    const unsigned short* __restrict__ W1T, const float* __restrict__ b1,
    unsigned short* __restrict__ h1g)
{
    __shared__ __align__(16) unsigned short nin_s[16*1024];
    int n0 = (blockIdx.x >> 1) * 16, half = blockIdx.x & 1, tid = threadIdx.x;
    for (int idx = tid; idx < 16*256; idx += 256) {
        int m = idx >> 8, q = idx & 255;
        int k4 = q * 4;
        float4 v = (k4 < 512) ? *(const float4*)&nf[(size_t)(n0+m)*512 + k4]
                              : *(const float4*)&agg[(size_t)(n0+m)*512 + (k4-512)];
        uint2 pk = { cvt_pk_bf16(v.x, v.y), cvt_pk_bf16(v.z, v.w) };
        *(uint2*)&nin_s[m*1024 + (k4 ^ ((m&7)<<3))] = pk;
    }
    __syncthreads();
    int w = tid >> 6, l = tid & 63, lj = l & 15, lh = l >> 4;
    f32x4 acc[4];
    #pragma unroll
    for (int nt = 0; nt < 4; ++nt) acc[nt] = (f32x4){0.f,0.f,0.f,0.f};
    for (int kt = 0; kt < 32; ++kt) {
        int k = kt*32 + lh*8;
        bf16x8 a = *(const bf16x8*)&nin_s[lj*1024 + (k ^ ((lj&7)<<3))];
        #pragma unroll
        for (int nt = 0; nt < 4; ++nt) {
            bf16x8 b = *(const bf16x8*)&W1T[(((size_t)kt*32 + half*16 + w*4 + nt)*64 + l)*8];
            acc[nt] = __builtin_amdgcn_mfma_f32_16x16x32_bf16(a, b, acc[nt], 0, 0, 0);
        }
    }
    #pragma unroll
    for (int nt = 0; nt < 4; ++nt) {
        int c = half*256 + w*64 + nt*16 + lj;
        float bv = b1[c];
        #pragma unroll
        for (int r = 0; r < 4; ++r)
            h1g[(size_t)(n0 + lh*4 + r)*512 + c] = f2bf(silu_f(acc[nt][r] + bv));
    }
}

// nf += silu(h1@nW2 + b2) ; 16 rows x 256 cols, 256 blocks
__global__ __launch_bounds__(256) void k_node2(
    float* __restrict__ nf, const unsigned short* __restrict__ h1g,
    const unsigned short* __restrict__ W2T, const float* __restrict__ b2)
{
    __shared__ __align__(16) unsigned short h1_s[16*512];
    int n0 = (blockIdx.x >> 1) * 16, half = blockIdx.x & 1, tid = threadIdx.x;
    for (int idx = tid; idx < 16*64; idx += 256) {
        int m = idx >> 6, k8 = (idx & 63) * 8;
        bf16x8 v = *(const bf16x8*)&h1g[(size_t)(n0+m)*512 + k8];
        *(bf16x8*)&h1_s[m*512 + (k8 ^ ((m&7)<<3))] = v;
    }
    __syncthreads();
    int w = tid >> 6, l = tid & 63, lj = l & 15, lh = l >> 4;
    f32x4 acc[4];
    #pragma unroll
    for (int nt = 0; nt < 4; ++nt) acc[nt] = (f32x4){0.f,0.f,0.f,0.f};
    for (int kt = 0; kt < 16; ++kt) {
        int k = kt*32 + lh*8;
        bf16x8 a = *(const bf16x8*)&h1_s[lj*512 + (k ^ ((lj&7)<<3))];
        #pragma unroll
        for (int nt = 0; nt < 4; ++nt) {
            bf16x8 b = *(const bf16x8*)&W2T[(((size_t)kt*32 + half*16 + w*4 + nt)*64 + l)*8];
            acc[nt] = __builtin_amdgcn_mfma_f32_16x16x32_bf16(a, b, acc[nt], 0, 0, 0);
        }
    }
    #pragma unroll
    for (int nt = 0; nt < 4; ++nt) {
        int c = half*256 + w*64 + nt*16 + lj;
        float bv = b2[c];
        #pragma unroll
        for (int r = 0; r < 4; ++r) {
            size_t o = (size_t)(n0 + lh*4 + r)*512 + c;
            nf[o] = nf[o] + silu_f(acc[nt][r] + bv);
        }
    }
}

// coord_out: 64 blocks x 256 thr; thread (node-local, k-slice) + 8-lane reduce
__global__ __launch_bounds__(256) void k_coord(const float* __restrict__ nf,
                                               const float* __restrict__ cW,
                                               float* __restrict__ out) {
    int b = blockIdx.x, t = threadIdx.x;
    int nl = t >> 3, s = t & 7;
    int n = b*32 + nl;
    const float* row = nf + (size_t)n*512 + s*64;
    float p0 = 0.f, p1 = 0.f, p2 = 0.f;
    #pragma unroll
    for (int k4 = 0; k4 < 64; k4 += 4) {
        float4 v = *(const float4*)&row[k4];
        int kg = s*64 + k4;
        p0 += v.x*cW[(kg+0)*3+0] + v.y*cW[(kg+1)*3+0] + v.z*cW[(kg+2)*3+0] + v.w*cW[(kg+3)*3+0];
        p1 += v.x*cW[(kg+0)*3+1] + v.y*cW[(kg+1)*3+1] + v.z*cW[(kg+2)*3+1] + v.w*cW[(kg+3)*3+1];
        p2 += v.x*cW[(kg+0)*3+2] + v.y*cW[(kg+1)*3+2] + v.z*cW[(kg+2)*3+2] + v.w*cW[(kg+3)*3+2];
    }
    p0 += __shfl_xor(p0, 1); p0 += __shfl_xor(p0, 2); p0 += __shfl_xor(p0, 4);
    p1 += __shfl_xor(p1, 1); p1 += __shfl_xor(p1, 2); p1 += __shfl_xor(p1, 4);
    p2 += __shfl_xor(p2, 1); p2 += __shfl_xor(p2, 2); p2 += __shfl_xor(p2, 4);
    if (s == 0) {
        out[576 + n*3 + 0] = p0;
        out[576 + n*3 + 1] = p1;
        out[576 + n*3 + 2] = p2;
    }
}

__global__ __launch_bounds__(256) void k_graph(const float* __restrict__ nf,
                                               const float* __restrict__ lW,
                                               const float* __restrict__ lat,
                                               float* __restrict__ out) {
    __shared__ float gf[512];
    __shared__ float lo9[9];
    int b = blockIdx.x, tid = threadIdx.x;
    float s0 = 0.f, s1 = 0.f;
    for (int r = 0; r < 32; ++r) {
        s0 += nf[(b * 32 + r) * 512 + tid];
        s1 += nf[(b * 32 + r) * 512 + tid + 256];
    }
    gf[tid]       = s0 * (1.f / 32.f);
    gf[tid + 256] = s1 * (1.f / 32.f);
    __syncthreads();
    if (tid < 9) {
        float s = 0.f;
        for (int k = 0; k < 512; ++k) s += gf[k] * lW[k * 9 + tid];
        lo9[tid] = s;
    }
    __syncthreads();
    if (tid < 9) {
        int i = tid / 3, kk = tid - (tid / 3) * 3;
        float s = lo9[i*3+0] * lat[b*9 + 0*3 + kk]
                + lo9[i*3+1] * lat[b*9 + 1*3 + kk]
                + lo9[i*3+2] * lat[b*9 + 2*3 + kk];
        out[b * 9 + tid] = s;
    }
}

extern "C" void kernel_launch(void* const* d_in, const int* in_sizes, int n_in,
                              void* d_out, int out_size, void* d_ws, size_t ws_size,
                              hipStream_t stream)
{
    const float* t    = (const float*)d_in[0];
    const float* frac = (const float*)d_in[1];
    const float* lat  = (const float*)d_in[2];
    const float* emb  = (const float*)d_in[3];
    const float* Wl   = (const float*)d_in[4];
    const float* bl   = (const float*)d_in[5];
    const float* eW1  = (const float*)d_in[6];
    const float* eb1  = (const float*)d_in[7];
    const float* eW2  = (const float*)d_in[8];
    const float* eb2  = (const float*)d_in[9];
    const float* nW1  = (const float*)d_in[10];
    const float* nb1  = (const float*)d_in[11];
    const float* nW2  = (const float*)d_in[12];
    const float* nb2  = (const float*)d_in[13];
    const float* cW   = (const float*)d_in[14];
    const float* lW   = (const float*)d_in[15];
    const int* atom_types = (const int*)d_in[16];

    float* out  = (float*)d_out;
    float* wsf  = (float*)d_ws;
    float* nf   = wsf + NF_OFF;
    float* Uagg = wsf + UAGG_OFF;   // U' during k_uv/k_edge, then agg (row-exclusive)
    float* VTD  = wsf + VTD_OFF;
    unsigned short* h1g = (unsigned short*)(wsf + H1_OFF);
    unsigned short* wbf = (unsigned short*)(wsf + WBF_OFF);
    unsigned short* fdP = (unsigned short*)(wsf + FDP_OFF);

    k_prep<<<384 + 4*1568, 256, 0, stream>>>(Wl, eW1, eW2, nW1, nW2, wbf);
    k_fd<<<1024, 64, 0, stream>>>(frac, fdP);
    k_init<<<256, 256, 0, stream>>>(t, emb, wbf, bl, atom_types, nf);
    for (int l = 0; l < 4; ++l) {
        const unsigned short* uvT  = wbf + SZ_INITT + (size_t)l * SZ_LAYER;
        const unsigned short* w1dT = uvT + SZ_UVT;
        const unsigned short* w2T  = w1dT + SZ_W1DT;
        const unsigned short* nw1T = w2T + SZ_W2T;
        const unsigned short* nw2T = nw1T + SZ_NW1T;
        k_uv<<<256, 256, 0, stream>>>(nf, uvT, lat,
                                      eW1 + (size_t)l*1093*512 + 1024*512,
                                      eb1 + l*512, Uagg, VTD);
        k_edge<<<1024, 512, 0, stream>>>(Uagg, VTD, fdP, w1dT, w2T,
                                         eb2 + l*512, Uagg);
        k_node1<<<256, 256, 0, stream>>>(nf, Uagg, nw1T, nb1 + l*512, h1g);
        k_node2<<<256, 256, 0, stream>>>(nf, h1g, nw2T, nb2 + l*512);
    }
    k_coord<<<64, 256, 0, stream>>>(nf, cW, out);
    k_graph<<<64, 256, 0, stream>>>(nf, lW, lat, out);
}